// Round 2
// baseline (164.437 us; speedup 1.0000x reference)
//
#include <hip/hip_runtime.h>
#include <hip/hip_bf16.h>

// Problem constants
#define NN    4096
#define INS_  256
#define OUTS_ 64
#define MM    4
#define LOG2E 1.4426950408889634f

typedef float f32x4 __attribute__((ext_vector_type(4)));
typedef short s16x8 __attribute__((ext_vector_type(8)));
typedef unsigned int u32x4 __attribute__((ext_vector_type(4)));

// pack two f32 into bf16x2 (round-to-nearest-even), returns u32
__device__ __forceinline__ unsigned int pack_bf16(float a, float b) {
    unsigned int ua = __builtin_bit_cast(unsigned int, a);
    unsigned int ub = __builtin_bit_cast(unsigned int, b);
    ua = (ua + 0x7FFFu + ((ua >> 16) & 1u)) >> 16;
    ub = (ub + 0x7FFFu + ((ub >> 16) & 1u)) & 0xFFFF0000u;
    return ua | ub;
}

// ws layout (floats):
//   [0,256)          pooled
//   [256,768)        gb: gamma[4][64] then beta[4][64]
//   [768,33536)      SUV float2[M][N]  = {2^{s'}, 2^{0.2 s'}}
//   [33536,66304)    SPQ float2[M][N]  = {2^{d'}, 2^{0.2 d'}}
//   [66304, ...)     Ht bf16 [M][64][4096]  (2 MB)
// total ~2.26 MB

// ---------- kernel 1a: column sums of x (atomic accumulate) ----------
__global__ void k_pool(const float* __restrict__ x, float* __restrict__ pooled) {
    const int t = threadIdx.x;
    const int r0 = blockIdx.x * 16;
    float s = 0.f;
    #pragma unroll
    for (int r = 0; r < 16; ++r) s += x[(r0 + r) * INS_ + t];
    atomicAdd(&pooled[t], s);
}

// ---------- kernel 1b: gamma/beta = pooled/N @ Wc + bc ----------
__global__ void k_cond(const float* __restrict__ pooled, const float* __restrict__ Wc,
                       const float* __restrict__ bc, float* __restrict__ gb) {
    __shared__ float sp[INS_];
    const int t = threadIdx.x;          // 0..511
    if (t < INS_) sp[t] = pooled[t] * (1.0f / NN);
    __syncthreads();
    float acc = bc[t];
    #pragma unroll 4
    for (int i = 0; i < INS_; ++i) acc = fmaf(sp[i], Wc[i * 512 + t], acc);
    gb[t] = acc;
}

// ---------- kernel 2: h = FiLM(x@W); emit Ht (bf16, transposed), SUV, SPQ ----------
__global__ __launch_bounds__(256) void k_film(
    const float* __restrict__ x, const float* __restrict__ W,
    const float* __restrict__ a1, const float* __restrict__ a2,
    const float* __restrict__ gb, float* __restrict__ suv,
    float* __restrict__ spq, __hip_bfloat16* __restrict__ ht)
{
    const int t  = threadIdx.x;
    const int o  = t & 63;
    const int wv = __builtin_amdgcn_readfirstlane(t >> 6);   // wave 0..3
    const int m  = blockIdx.y;
    const int n0 = blockIdx.x * 32 + wv * 8;                 // this wave's 8 rows

    float acc[8];
    #pragma unroll
    for (int k = 0; k < 8; ++k) acc[k] = 0.f;

    const float* wp = W + (size_t)m * INS_ * OUTS_ + o;      // W[m][i][o]
    const float* xp = x + (size_t)n0 * INS_;                 // uniform rows -> s_load

    #pragma unroll 4
    for (int i = 0; i < INS_; ++i) {
        const float wl = wp[(size_t)i * OUTS_];
        #pragma unroll
        for (int k = 0; k < 8; ++k)
            acc[k] = fmaf(xp[k * INS_ + i], wl, acc[k]);
    }

    const float ga  = gb[m * 64 + o];
    const float be  = gb[256 + m * 64 + o];
    const float va1 = a1[m * 64 + o];
    const float va2 = a2[m * 64 + o];

    float h[8], sv[8], dv[8];
    #pragma unroll
    for (int k = 0; k < 8; ++k) h[k] = fmaf(ga, acc[k], be);

    // per-row dot with a1/a2: butterfly over the 64 o-lanes
    #pragma unroll
    for (int k = 0; k < 8; ++k) {
        float s1 = h[k] * va1;
        float s2 = h[k] * va2;
        #pragma unroll
        for (int off = 1; off < 64; off <<= 1) {
            s1 += __shfl_xor(s1, off);
            s2 += __shfl_xor(s2, off);
        }
        sv[k] = s1; dv[k] = s2;
    }

    // Ht[m][o][n0..n0+7] as bf16 (one 16B store)
    u32x4 upk;
    upk.x = pack_bf16(h[0], h[1]);
    upk.y = pack_bf16(h[2], h[3]);
    upk.z = pack_bf16(h[4], h[5]);
    upk.w = pack_bf16(h[6], h[7]);
    *reinterpret_cast<u32x4*>(&ht[(size_t)(m * 64 + o) * NN + n0]) = upk;

    // SUV/SPQ: lanes 0..7 write source factors, 8..15 write dest factors
    const int lk = o & 7;
    float ssel = sv[0], dsel = dv[0];
    #pragma unroll
    for (int k = 1; k < 8; ++k) {
        if (lk == k) { ssel = sv[k]; dsel = dv[k]; }
    }
    if (o < 16) {
        const float base = (o < 8) ? ssel : dsel;
        const float spv  = base * LOG2E;
        float2 ex = make_float2(exp2f(spv), exp2f(0.2f * spv));
        float* dst = ((o < 8) ? suv : spq) + (size_t)(m * NN + n0 + lk) * 2;
        *reinterpret_cast<float2*>(dst) = ex;
    }
}

// ---------- kernel 3: fused masked softmax + PV (bf16 MFMA) ----------
__global__ __launch_bounds__(512, 2) void k_attn(
    const int* __restrict__ adj, const float* __restrict__ suv,
    const float* __restrict__ spq, const __hip_bfloat16* __restrict__ ht,
    float* __restrict__ out)
{
    __shared__ float accL[8][16][64];
    __shared__ float zL[8][16];

    const int t    = threadIdx.x;
    const int lane = t & 63;
    const int w    = __builtin_amdgcn_readfirstlane(t >> 6); // wave 0..7
    const int mech = w & 3;
    const int jh   = w >> 2;
    const int col  = lane & 15;       // A-row index / B-col index
    const int kg   = lane >> 4;       // k-group 0..3
    const int kb   = kg * 8;
    const int i0   = blockIdx.x * 16;
    const int i    = i0 + col;

    const float2 uv = *reinterpret_cast<const float2*>(&suv[(size_t)(mech * NN + i) * 2]);
    const float U = uv.x, V = uv.y;

    const int* __restrict__ arow = adj + (size_t)i * NN;
    const float* __restrict__ pqb = spq + (size_t)mech * NN * 2;
    const __hip_bfloat16* __restrict__ hb = ht + (size_t)(mech * 64 + col) * NN;

    f32x4 acc0 = {0.f, 0.f, 0.f, 0.f};
    f32x4 acc1 = acc0, acc2 = acc0, acc3 = acc0;
    float Z = 0.f;
    const int jbase = jh * 2048 + kb;

    #pragma unroll 2
    for (int jt = 0; jt < 2048; jt += 32) {
        const int j0 = jbase + jt;
        const int4 A0 = *reinterpret_cast<const int4*>(&arow[j0]);
        const int4 A1 = *reinterpret_cast<const int4*>(&arow[j0 + 4]);
        const float4 pq0 = *reinterpret_cast<const float4*>(&pqb[j0 * 2]);
        const float4 pq1 = *reinterpret_cast<const float4*>(&pqb[j0 * 2 + 4]);
        const float4 pq2 = *reinterpret_cast<const float4*>(&pqb[j0 * 2 + 8]);
        const float4 pq3 = *reinterpret_cast<const float4*>(&pqb[j0 * 2 + 12]);
        const s16x8 B0 = *reinterpret_cast<const s16x8*>(&hb[j0]);
        const s16x8 B1 = *reinterpret_cast<const s16x8*>(&hb[16 * NN + j0]);
        const s16x8 B2 = *reinterpret_cast<const s16x8*>(&hb[32 * NN + j0]);
        const s16x8 B3 = *reinterpret_cast<const s16x8*>(&hb[48 * NN + j0]);

        // w = adj * exp(leaky(s+d)) = adj * max(U*P, V*Q)
        const float w0 = (float)A0.x * fmaxf(U * pq0.x, V * pq0.y);
        const float w1 = (float)A0.y * fmaxf(U * pq0.z, V * pq0.w);
        const float w2 = (float)A0.z * fmaxf(U * pq1.x, V * pq1.y);
        const float w3 = (float)A0.w * fmaxf(U * pq1.z, V * pq1.w);
        const float w4 = (float)A1.x * fmaxf(U * pq2.x, V * pq2.y);
        const float w5 = (float)A1.y * fmaxf(U * pq2.z, V * pq2.w);
        const float w6 = (float)A1.z * fmaxf(U * pq3.x, V * pq3.y);
        const float w7 = (float)A1.w * fmaxf(U * pq3.z, V * pq3.w);

        Z += ((w0 + w1) + (w2 + w3)) + ((w4 + w5) + (w6 + w7));

        u32x4 au;
        au.x = pack_bf16(w0, w1);
        au.y = pack_bf16(w2, w3);
        au.z = pack_bf16(w4, w5);
        au.w = pack_bf16(w6, w7);
        const s16x8 Af = __builtin_bit_cast(s16x8, au);

        acc0 = __builtin_amdgcn_mfma_f32_16x16x32_bf16(Af, B0, acc0, 0, 0, 0);
        acc1 = __builtin_amdgcn_mfma_f32_16x16x32_bf16(Af, B1, acc1, 0, 0, 0);
        acc2 = __builtin_amdgcn_mfma_f32_16x16x32_bf16(Af, B2, acc2, 0, 0, 0);
        acc3 = __builtin_amdgcn_mfma_f32_16x16x32_bf16(Af, B3, acc3, 0, 0, 0);
    }

    // row-sum Z: lanes {r, r+16, r+32, r+48} hold the same row
    Z += __shfl_xor(Z, 16);
    Z += __shfl_xor(Z, 32);

    #pragma unroll
    for (int rr = 0; rr < 4; ++rr) {
        const int row = kg * 4 + rr;   // C-frag: row = (lane>>4)*4 + reg
        accL[w][row][ 0 + col] = acc0[rr];
        accL[w][row][16 + col] = acc1[rr];
        accL[w][row][32 + col] = acc2[rr];
        accL[w][row][48 + col] = acc3[rr];
    }
    if (lane < 16) zL[w][lane] = Z;
    __syncthreads();

    // combine j-halves, normalize, ELU, store
    const int row = t >> 5;            // 0..15
    const int cb  = (t & 31) * 8;      // 0..248
    const int m2  = cb >> 6;
    const int oo  = cb & 63;
    const float zs  = zL[m2][row] + zL[m2 + 4][row];
    const float inv = 1.0f / zs;
    const float* pa = &accL[m2][row][oo];
    const float* pb = &accL[m2 + 4][row][oo];
    float res[8];
    #pragma unroll
    for (int e = 0; e < 8; ++e) {
        const float v = (pa[e] + pb[e]) * inv;
        res[e] = v > 0.f ? v : expm1f(v);
    }
    float* op = out + (size_t)(i0 + row) * 256 + cb;
    *reinterpret_cast<float4*>(op)     = make_float4(res[0], res[1], res[2], res[3]);
    *reinterpret_cast<float4*>(op + 4) = make_float4(res[4], res[5], res[6], res[7]);
}

extern "C" void kernel_launch(void* const* d_in, const int* in_sizes, int n_in,
                              void* d_out, int out_size, void* d_ws, size_t ws_size,
                              hipStream_t stream) {
    const float* x   = (const float*)d_in[0];
    const int*   adj = (const int*)d_in[1];
    const float* W   = (const float*)d_in[2];
    const float* a1  = (const float*)d_in[3];
    const float* a2  = (const float*)d_in[4];
    const float* Wc  = (const float*)d_in[5];
    const float* bc  = (const float*)d_in[6];
    float* out = (float*)d_out;

    float* wsf    = (float*)d_ws;
    float* pooled = wsf;
    float* gbv    = wsf + 256;
    float* suv    = wsf + 768;
    float* spq    = wsf + 768 + 2 * MM * NN;
    __hip_bfloat16* ht = (__hip_bfloat16*)(wsf + 768 + 4 * MM * NN);

    (void)hipMemsetAsync(pooled, 0, INS_ * sizeof(float), stream);
    k_pool<<<256, 256, 0, stream>>>(x, pooled);
    k_cond<<<1, 512, 0, stream>>>(pooled, Wc, bc, gbv);
    k_film<<<dim3(128, 4), 256, 0, stream>>>(x, W, a1, a2, gbv, suv, spq, ht);
    k_attn<<<256, 512, 0, stream>>>(adj, suv, spq, ht, out);
}

// Round 3
// 133.063 us; speedup vs baseline: 1.2358x; 1.2358x over previous
//
#include <hip/hip_runtime.h>
#include <hip/hip_bf16.h>

// Problem constants
#define NN    4096
#define INS_  256
#define OUTS_ 64
#define MM    4
#define LOG2E 1.4426950408889634f

typedef float f32x4 __attribute__((ext_vector_type(4)));
typedef short s16x8 __attribute__((ext_vector_type(8)));
typedef unsigned int u32x4 __attribute__((ext_vector_type(4)));

typedef const __attribute__((address_space(1))) unsigned char glob_u8;
typedef __attribute__((address_space(3))) unsigned char lds_u8;

__device__ __forceinline__ void stage16(const void* g, void* l) {
    __builtin_amdgcn_global_load_lds((glob_u8*)g, (lds_u8*)l, 16, 0, 0);
}

__device__ __forceinline__ unsigned int cvt_pk_bf16(float a, float b) {
    unsigned int r;
    asm("v_cvt_pk_bf16_f32 %0, %1, %2" : "=v"(r) : "v"(a), "v"(b));
    return r;
}

// pack two f32 into bf16x2 (RNE) - VALU fallback used in k_film (not hot)
__device__ __forceinline__ unsigned int pack_bf16(float a, float b) {
    unsigned int ua = __builtin_bit_cast(unsigned int, a);
    unsigned int ub = __builtin_bit_cast(unsigned int, b);
    ua = (ua + 0x7FFFu + ((ua >> 16) & 1u)) >> 16;
    ub = (ub + 0x7FFFu + ((ub >> 16) & 1u)) & 0xFFFF0000u;
    return ua | ub;
}

// ws layout (floats):
//   [0,256)        pooled
//   [256,768)      gb: gamma[4][64] then beta[4][64]
//   [768,33536)    SUV float2[M][N]  = {2^{s'}, 2^{0.2 s'}}
//   [33536,66304)  SPQ float2[M][N]  = {2^{d'}, 2^{0.2 d'}}
//   [66304,...)    Ht bf16, swizzled tiles: [m][jt=n/32][4KB tile]
//                  tile phys(o, jj): o*64 + ((kg ^ ((o>>1)&3))<<4) + e*2,  kg=jj>>3, e=jj&7

// ---------- kernel 1a: column sums of x ----------
__global__ void k_pool(const float* __restrict__ x, float* __restrict__ pooled) {
    const int t = threadIdx.x;
    const int r0 = blockIdx.x * 16;
    float s = 0.f;
    #pragma unroll
    for (int r = 0; r < 16; ++r) s += x[(r0 + r) * INS_ + t];
    atomicAdd(&pooled[t], s);
}

// ---------- kernel 1b: gamma/beta ----------
__global__ void k_cond(const float* __restrict__ pooled, const float* __restrict__ Wc,
                       const float* __restrict__ bc, float* __restrict__ gb) {
    __shared__ float sp[INS_];
    const int t = threadIdx.x;          // 0..511
    if (t < INS_) sp[t] = pooled[t] * (1.0f / NN);
    __syncthreads();
    float acc = bc[t];
    #pragma unroll 4
    for (int i = 0; i < INS_; ++i) acc = fmaf(sp[i], Wc[i * 512 + t], acc);
    gb[t] = acc;
}

// ---------- kernel 2: h = FiLM(x@W); emit swizzled-tiled Ht, SUV, SPQ ----------
__global__ __launch_bounds__(256) void k_film(
    const float* __restrict__ x, const float* __restrict__ W,
    const float* __restrict__ a1, const float* __restrict__ a2,
    const float* __restrict__ gb, float* __restrict__ suv,
    float* __restrict__ spq, unsigned char* __restrict__ htb)
{
    const int t  = threadIdx.x;
    const int o  = t & 63;
    const int wv = __builtin_amdgcn_readfirstlane(t >> 6);   // wave 0..3
    const int m  = blockIdx.y;
    const int n0 = blockIdx.x * 32 + wv * 8;                 // this wave's 8 rows

    float acc[8];
    #pragma unroll
    for (int k = 0; k < 8; ++k) acc[k] = 0.f;

    const float* wp = W + (size_t)m * INS_ * OUTS_ + o;
    const float* xp = x + (size_t)n0 * INS_;

    #pragma unroll 4
    for (int i = 0; i < INS_; ++i) {
        const float wl = wp[(size_t)i * OUTS_];
        #pragma unroll
        for (int k = 0; k < 8; ++k)
            acc[k] = fmaf(xp[k * INS_ + i], wl, acc[k]);
    }

    const float ga  = gb[m * 64 + o];
    const float be  = gb[256 + m * 64 + o];
    const float va1 = a1[m * 64 + o];
    const float va2 = a2[m * 64 + o];

    float h[8], sv[8], dv[8];
    #pragma unroll
    for (int k = 0; k < 8; ++k) h[k] = fmaf(ga, acc[k], be);

    #pragma unroll
    for (int k = 0; k < 8; ++k) {
        float s1 = h[k] * va1;
        float s2 = h[k] * va2;
        #pragma unroll
        for (int off = 1; off < 64; off <<= 1) {
            s1 += __shfl_xor(s1, off);
            s2 += __shfl_xor(s2, off);
        }
        sv[k] = s1; dv[k] = s2;
    }

    // swizzled-tile store: tile jt = blockIdx.x, kg = wv
    u32x4 upk;
    upk.x = pack_bf16(h[0], h[1]);
    upk.y = pack_bf16(h[2], h[3]);
    upk.z = pack_bf16(h[4], h[5]);
    upk.w = pack_bf16(h[6], h[7]);
    const size_t phys = ((size_t)(m * 128 + blockIdx.x)) * 4096
                      + o * 64 + ((wv ^ ((o >> 1) & 3)) << 4);
    *reinterpret_cast<u32x4*>(htb + phys) = upk;

    // SUV/SPQ
    const int lk = o & 7;
    float ssel = sv[0], dsel = dv[0];
    #pragma unroll
    for (int k = 1; k < 8; ++k) {
        if (lk == k) { ssel = sv[k]; dsel = dv[k]; }
    }
    if (o < 16) {
        const float base = (o < 8) ? ssel : dsel;
        const float spv  = base * LOG2E;
        float2 ex = make_float2(exp2f(spv), exp2f(0.2f * spv));
        float* dst = ((o < 8) ? suv : spq) + (size_t)(m * NN + n0 + lk) * 2;
        *reinterpret_cast<float2*>(dst) = ex;
    }
}

// ---------- kernel 3: fused masked softmax + PV ----------
// grid (128, 2): x = i-tile (32 rows), y = mech-pair. 512 thr = 8 waves.
// wave w: mech_loc = w&1, jq = w>>1 (j window jq*1024..+1024), 2 i-subtiles.
// dyn LDS 64KB: 2 bufs x 8 tiles x 4KB. Epilogue combines jq partials in LDS.
__global__ __launch_bounds__(512, 1) void k_attn(
    const int* __restrict__ adj, const float* __restrict__ suv,
    const float* __restrict__ spq, const unsigned char* __restrict__ htb,
    float* __restrict__ out)
{
    extern __shared__ unsigned char lds[];

    const int t    = threadIdx.x;
    const int lane = t & 63;
    const int w    = __builtin_amdgcn_readfirstlane(t >> 6); // wave 0..7
    const int col  = lane & 15;
    const int kg   = lane >> 4;
    const int i0   = blockIdx.x * 32;
    const int mp   = blockIdx.y;              // mech pair
    const int mloc = w & 1;
    const int jq   = w >> 1;                  // 0..3
    const int mech = mp * 2 + mloc;

    // staging role: wave w stages tile tau=w = (ms = w>>2, jqs = w&3), 4 quarters
    const int ms  = w >> 2;
    const int jqs = w & 3;
    const unsigned char* gtile_base = htb
        + ((size_t)((mp * 2 + ms) * 128 + jqs * 32)) * 4096 + lane * 16;

    // compute-side LDS tile base + swizzled per-lane frag offsets (constant over t)
    const int ctile = (mloc * 4 + jq) * 4096;
    int boff[4];
    #pragma unroll
    for (int f = 0; f < 4; ++f) {
        const int o = f * 16 + col;
        boff[f] = ctile + o * 64 + ((kg ^ ((o >> 1) & 3)) << 4);
    }

    // per-i U,V (2 subtiles)
    float Us[2], Vs[2];
    #pragma unroll
    for (int s = 0; s < 2; ++s) {
        const float2 uv = *reinterpret_cast<const float2*>(
            &suv[(size_t)(mech * NN + i0 + s * 16 + col) * 2]);
        Us[s] = uv.x; Vs[s] = uv.y;
    }
    const int* arow0 = adj + (size_t)(i0 + col) * NN;
    const int* arow1 = adj + (size_t)(i0 + 16 + col) * NN;
    const float* pqb = spq + (size_t)mech * NN * 2;

    const s16x8 ones = __builtin_bit_cast(s16x8,
        (u32x4){0x3F803F80u, 0x3F803F80u, 0x3F803F80u, 0x3F803F80u});

    f32x4 acc[2][4];
    f32x4 accZ[2];
    #pragma unroll
    for (int s = 0; s < 2; ++s) {
        accZ[s] = (f32x4){0.f, 0.f, 0.f, 0.f};
        #pragma unroll
        for (int f = 0; f < 4; ++f) acc[s][f] = (f32x4){0.f, 0.f, 0.f, 0.f};
    }

    // prologue: stage t=0 into buf 0
    {
        unsigned char* ld0 = lds + w * 4096;
        const unsigned char* g = gtile_base;   // tn = 0
        stage16(g,        ld0);
        stage16(g + 1024, ld0 + 1024);
        stage16(g + 2048, ld0 + 2048);
        stage16(g + 3072, ld0 + 3072);
    }
    __syncthreads();

    int buf = 0;
    #pragma unroll 1
    for (int tn = 0; tn < 32; ++tn) {
        // issue next-step staging
        if (tn < 31) {
            unsigned char* ld1 = lds + (buf ^ 1) * 32768 + w * 4096;
            const unsigned char* g = gtile_base + (size_t)(tn + 1) * 4096;
            stage16(g,        ld1);
            stage16(g + 1024, ld1 + 1024);
            stage16(g + 2048, ld1 + 2048);
            stage16(g + 3072, ld1 + 3072);
        }

        const int j0 = jq * 1024 + tn * 32 + kg * 8;

        // global loads early
        const int4 a00 = *reinterpret_cast<const int4*>(arow0 + j0);
        const int4 a01 = *reinterpret_cast<const int4*>(arow0 + j0 + 4);
        const int4 a10 = *reinterpret_cast<const int4*>(arow1 + j0);
        const int4 a11 = *reinterpret_cast<const int4*>(arow1 + j0 + 4);
        const float4 q0 = *reinterpret_cast<const float4*>(&pqb[j0 * 2]);
        const float4 q1 = *reinterpret_cast<const float4*>(&pqb[j0 * 2 + 4]);
        const float4 q2 = *reinterpret_cast<const float4*>(&pqb[j0 * 2 + 8]);
        const float4 q3 = *reinterpret_cast<const float4*>(&pqb[j0 * 2 + 12]);

        // B frags from LDS (swizzled, ~conflict-free)
        const unsigned char* lb = lds + buf * 32768;
        const s16x8 B0 = *reinterpret_cast<const s16x8*>(lb + boff[0]);
        const s16x8 B1 = *reinterpret_cast<const s16x8*>(lb + boff[1]);
        const s16x8 B2 = *reinterpret_cast<const s16x8*>(lb + boff[2]);
        const s16x8 B3 = *reinterpret_cast<const s16x8*>(lb + boff[3]);

        // weights for both subtiles
        s16x8 Af[2];
        #pragma unroll
        for (int s = 0; s < 2; ++s) {
            const float U = Us[s], V = Vs[s];
            const int4 a0 = s ? a10 : a00;
            const int4 a1 = s ? a11 : a01;
            const float w0 = a0.x ? fmaxf(U * q0.x, V * q0.y) : 0.f;
            const float w1 = a0.y ? fmaxf(U * q0.z, V * q0.w) : 0.f;
            const float w2 = a0.z ? fmaxf(U * q1.x, V * q1.y) : 0.f;
            const float w3 = a0.w ? fmaxf(U * q1.z, V * q1.w) : 0.f;
            const float w4 = a1.x ? fmaxf(U * q2.x, V * q2.y) : 0.f;
            const float w5 = a1.y ? fmaxf(U * q2.z, V * q2.w) : 0.f;
            const float w6 = a1.z ? fmaxf(U * q3.x, V * q3.y) : 0.f;
            const float w7 = a1.w ? fmaxf(U * q3.z, V * q3.w) : 0.f;
            u32x4 au;
            au.x = cvt_pk_bf16(w0, w1);
            au.y = cvt_pk_bf16(w2, w3);
            au.z = cvt_pk_bf16(w4, w5);
            au.w = cvt_pk_bf16(w6, w7);
            Af[s] = __builtin_bit_cast(s16x8, au);
        }

        #pragma unroll
        for (int s = 0; s < 2; ++s) {
            acc[s][0] = __builtin_amdgcn_mfma_f32_16x16x32_bf16(Af[s], B0, acc[s][0], 0, 0, 0);
            acc[s][1] = __builtin_amdgcn_mfma_f32_16x16x32_bf16(Af[s], B1, acc[s][1], 0, 0, 0);
            acc[s][2] = __builtin_amdgcn_mfma_f32_16x16x32_bf16(Af[s], B2, acc[s][2], 0, 0, 0);
            acc[s][3] = __builtin_amdgcn_mfma_f32_16x16x32_bf16(Af[s], B3, acc[s][3], 0, 0, 0);
            accZ[s]   = __builtin_amdgcn_mfma_f32_16x16x32_bf16(Af[s], ones, accZ[s], 0, 0, 0);
        }

        __syncthreads();   // drains staging vmcnt; next buf ready
        buf ^= 1;
    }

    // ---- epilogue: combine 4 jq partials in (dead) staging LDS ----
    float* accF = reinterpret_cast<float*>(lds);            // [2][32][64] = 16KB
    float* zF   = reinterpret_cast<float*>(lds + 16384);    // [2][32]

    #pragma unroll 1
    for (int p = 0; p < 4; ++p) {
        if (jq == p) {
            #pragma unroll
            for (int s = 0; s < 2; ++s) {
                #pragma unroll
                for (int f = 0; f < 4; ++f) {
                    #pragma unroll
                    for (int rr = 0; rr < 4; ++rr) {
                        const int idx = (mloc * 32 + s * 16 + kg * 4 + rr) * 64 + f * 16 + col;
                        if (p == 0) accF[idx] = acc[s][f][rr];
                        else        accF[idx] += acc[s][f][rr];
                    }
                }
                if (col == 0) {
                    #pragma unroll
                    for (int rr = 0; rr < 4; ++rr) {
                        const int zi = mloc * 32 + s * 16 + kg * 4 + rr;
                        if (p == 0) zF[zi] = accZ[s][rr];
                        else        zF[zi] += accZ[s][rr];
                    }
                }
            }
        }
        __syncthreads();
    }

    // normalize + ELU + store: thread t handles 8 consecutive outputs
    const int f0    = t * 8;
    const int emloc = f0 >> 11;
    const int iloc  = (f0 >> 6) & 31;
    const int o0    = f0 & 63;
    const float inv = 1.0f / zF[emloc * 32 + iloc];
    const float* pa = &accF[f0];
    float res[8];
    #pragma unroll
    for (int e = 0; e < 8; ++e) {
        const float v = pa[e] * inv;
        res[e] = v > 0.f ? v : expm1f(v);
    }
    float* op = out + (size_t)(i0 + iloc) * 256 + (mp * 2 + emloc) * 64 + o0;
    *reinterpret_cast<float4*>(op)     = make_float4(res[0], res[1], res[2], res[3]);
    *reinterpret_cast<float4*>(op + 4) = make_float4(res[4], res[5], res[6], res[7]);
}

extern "C" void kernel_launch(void* const* d_in, const int* in_sizes, int n_in,
                              void* d_out, int out_size, void* d_ws, size_t ws_size,
                              hipStream_t stream) {
    const float* x   = (const float*)d_in[0];
    const int*   adj = (const int*)d_in[1];
    const float* W   = (const float*)d_in[2];
    const float* a1  = (const float*)d_in[3];
    const float* a2  = (const float*)d_in[4];
    const float* Wc  = (const float*)d_in[5];
    const float* bc  = (const float*)d_in[6];
    float* out = (float*)d_out;

    float* wsf    = (float*)d_ws;
    float* pooled = wsf;
    float* gbv    = wsf + 256;
    float* suv    = wsf + 768;
    float* spq    = wsf + 768 + 2 * MM * NN;
    unsigned char* htb = (unsigned char*)(wsf + 768 + 4 * MM * NN);

    (void)hipFuncSetAttribute((const void*)k_attn,
                              hipFuncAttributeMaxDynamicSharedMemorySize, 65536);

    (void)hipMemsetAsync(pooled, 0, INS_ * sizeof(float), stream);
    k_pool<<<256, 256, 0, stream>>>(x, pooled);
    k_cond<<<1, 512, 0, stream>>>(pooled, Wc, bc, gbv);
    k_film<<<dim3(128, 4), 256, 0, stream>>>(x, W, a1, a2, gbv, suv, spq, htb);
    k_attn<<<dim3(128, 2), 512, 65536, stream>>>(adj, suv, spq, htb, out);
}

// Round 4
// 126.606 us; speedup vs baseline: 1.2988x; 1.0510x over previous
//
#include <hip/hip_runtime.h>
#include <hip/hip_bf16.h>

// Problem constants
#define NN    4096
#define INS_  256
#define OUTS_ 64
#define MM    4
#define LOG2E 1.4426950408889634f

typedef float f32x4 __attribute__((ext_vector_type(4)));
typedef short s16x8 __attribute__((ext_vector_type(8)));
typedef unsigned int u32x4 __attribute__((ext_vector_type(4)));

__device__ __forceinline__ unsigned int cvt_pk_bf16(float a, float b) {
    unsigned int r;
    asm("v_cvt_pk_bf16_f32 %0, %1, %2" : "=v"(r) : "v"(a), "v"(b));
    return r;
}

// pack two f32 into bf16x2 (RNE) - VALU fallback used in k_film (not hot)
__device__ __forceinline__ unsigned int pack_bf16(float a, float b) {
    unsigned int ua = __builtin_bit_cast(unsigned int, a);
    unsigned int ub = __builtin_bit_cast(unsigned int, b);
    ua = (ua + 0x7FFFu + ((ua >> 16) & 1u)) >> 16;
    ub = (ub + 0x7FFFu + ((ub >> 16) & 1u)) & 0xFFFF0000u;
    return ua | ub;
}

// ws layout (floats):
//   [0,256)        pooled
//   [256,768)      gb: gamma[4][64] then beta[4][64]
//   [768,33536)    SUV float2[M][N]  = {2^{s'}, 2^{0.2 s'}}
//   [33536,66304)  SPQ float2[M][N]  = {2^{d'}, 2^{0.2 d'}}
//   byte 265216    Ht bf16 tiles [m][jt=0..127][4KB]: tile(o,jj) at o*64+jj*2  (2 MB)
//   byte 2362368   adj bitmask [N][512B]: bit j of row r = adj[r][j]!=0       (2 MB)

// ---------- kernel 0: pack adjacency to bitmask ----------
__global__ __launch_bounds__(256) void k_pack(const int* __restrict__ adj,
                                              unsigned long long* __restrict__ msk) {
    const int lane = threadIdx.x & 63;
    const int w    = threadIdx.x >> 6;
    const int r    = blockIdx.x * 4 + w;
    const int* row = adj + (size_t)r * NN;
    unsigned long long* mrow = msk + (size_t)r * 64;
    #pragma unroll 4
    for (int c = 0; c < 64; ++c) {
        const int a = row[c * 64 + lane];
        const unsigned long long m = __ballot(a != 0);
        if (lane == 0) mrow[c] = m;
    }
}

// ---------- kernel 1a: column sums of x ----------
__global__ void k_pool(const float* __restrict__ x, float* __restrict__ pooled) {
    const int t = threadIdx.x;
    const int r0 = blockIdx.x * 16;
    float s = 0.f;
    #pragma unroll
    for (int r = 0; r < 16; ++r) s += x[(r0 + r) * INS_ + t];
    atomicAdd(&pooled[t], s);
}

// ---------- kernel 1b: gamma/beta ----------
__global__ void k_cond(const float* __restrict__ pooled, const float* __restrict__ Wc,
                       const float* __restrict__ bc, float* __restrict__ gb) {
    __shared__ float sp[INS_];
    const int t = threadIdx.x;          // 0..511
    if (t < INS_) sp[t] = pooled[t] * (1.0f / NN);
    __syncthreads();
    float acc = bc[t];
    #pragma unroll 4
    for (int i = 0; i < INS_; ++i) acc = fmaf(sp[i], Wc[i * 512 + t], acc);
    gb[t] = acc;
}

// ---------- kernel 2: h = FiLM(x@W); emit tiled Ht, SUV, SPQ ----------
__global__ __launch_bounds__(256) void k_film(
    const float* __restrict__ x, const float* __restrict__ W,
    const float* __restrict__ a1, const float* __restrict__ a2,
    const float* __restrict__ gb, float* __restrict__ suv,
    float* __restrict__ spq, unsigned char* __restrict__ htb)
{
    const int t  = threadIdx.x;
    const int o  = t & 63;
    const int wv = __builtin_amdgcn_readfirstlane(t >> 6);   // wave 0..3
    const int m  = blockIdx.y;
    const int n0 = blockIdx.x * 32 + wv * 8;                 // this wave's 8 rows

    float acc[8];
    #pragma unroll
    for (int k = 0; k < 8; ++k) acc[k] = 0.f;

    const float* wp = W + (size_t)m * INS_ * OUTS_ + o;
    const float* xp = x + (size_t)n0 * INS_;

    #pragma unroll 4
    for (int i = 0; i < INS_; ++i) {
        const float wl = wp[(size_t)i * OUTS_];
        #pragma unroll
        for (int k = 0; k < 8; ++k)
            acc[k] = fmaf(xp[k * INS_ + i], wl, acc[k]);
    }

    const float ga  = gb[m * 64 + o];
    const float be  = gb[256 + m * 64 + o];
    const float va1 = a1[m * 64 + o];
    const float va2 = a2[m * 64 + o];

    float h[8], sv[8], dv[8];
    #pragma unroll
    for (int k = 0; k < 8; ++k) h[k] = fmaf(ga, acc[k], be);

    #pragma unroll
    for (int k = 0; k < 8; ++k) {
        float s1 = h[k] * va1;
        float s2 = h[k] * va2;
        #pragma unroll
        for (int off = 1; off < 64; off <<= 1) {
            s1 += __shfl_xor(s1, off);
            s2 += __shfl_xor(s2, off);
        }
        sv[k] = s1; dv[k] = s2;
    }

    // tile store: tile jt = blockIdx.x, rows jj = wv*8..wv*8+7
    u32x4 upk;
    upk.x = pack_bf16(h[0], h[1]);
    upk.y = pack_bf16(h[2], h[3]);
    upk.z = pack_bf16(h[4], h[5]);
    upk.w = pack_bf16(h[6], h[7]);
    const size_t phys = ((size_t)(m * 128 + blockIdx.x)) * 4096 + o * 64 + wv * 16;
    *reinterpret_cast<u32x4*>(htb + phys) = upk;

    // SUV/SPQ
    const int lk = o & 7;
    float ssel = sv[0], dsel = dv[0];
    #pragma unroll
    for (int k = 1; k < 8; ++k) {
        if (lk == k) { ssel = sv[k]; dsel = dv[k]; }
    }
    if (o < 16) {
        const float base = (o < 8) ? ssel : dsel;
        const float spv  = base * LOG2E;
        float2 ex = make_float2(exp2f(spv), exp2f(0.2f * spv));
        float* dst = ((o < 8) ? suv : spq) + (size_t)(m * NN + n0 + lk) * 2;
        *reinterpret_cast<float2*>(dst) = ex;
    }
}

// ---------- kernel 3: fused masked softmax + PV, no main-loop LDS ----------
// grid (128, 2): x = i-tile (32 rows), y = mech-pair. 512 thr = 8 waves.
// wave w: mloc = w&1 (mech), jq = w>>1 (j window jq*1024..+1024), 2 i-subtiles.
__global__ __launch_bounds__(512, 1) void k_attn(
    const unsigned int* __restrict__ msk, const float* __restrict__ suv,
    const float* __restrict__ spq, const unsigned char* __restrict__ htb,
    float* __restrict__ out)
{
    __shared__ float accF[2 * 32 * 64];
    __shared__ float zF[2 * 32];

    const int t    = threadIdx.x;
    const int lane = t & 63;
    const int w    = __builtin_amdgcn_readfirstlane(t >> 6); // wave 0..7
    const int col  = lane & 15;
    const int kg   = lane >> 4;
    const int i0   = blockIdx.x * 32;
    const int mp   = blockIdx.y;
    const int mloc = w & 1;
    const int jq   = w >> 1;                  // 0..3
    const int mech = mp * 2 + mloc;

    // per-i U,V (2 subtiles)
    float Us[2], Vs[2];
    #pragma unroll
    for (int s = 0; s < 2; ++s) {
        const float2 uv = *reinterpret_cast<const float2*>(
            &suv[(size_t)(mech * NN + i0 + s * 16 + col) * 2]);
        Us[s] = uv.x; Vs[s] = uv.y;
    }
    const unsigned int* mrow0 = msk + (size_t)(i0 + col) * 128 + jq * 32;
    const unsigned int* mrow1 = mrow0 + 16 * 128;
    const float* pqb = spq + (size_t)mech * NN * 2;
    // per-lane Ht base: tile jt = jq*32 + tn; lane reads 16B at (f*16+col)*64 + kg*16
    const unsigned char* tb0 = htb + ((size_t)(mech * 128 + jq * 32)) * 4096
                             + col * 64 + kg * 16;

    const s16x8 ones = __builtin_bit_cast(s16x8,
        (u32x4){0x3F803F80u, 0x3F803F80u, 0x3F803F80u, 0x3F803F80u});

    f32x4 acc[2][4];
    f32x4 accZ[2];
    #pragma unroll
    for (int s = 0; s < 2; ++s) {
        accZ[s] = (f32x4){0.f, 0.f, 0.f, 0.f};
        #pragma unroll
        for (int f = 0; f < 4; ++f) acc[s][f] = (f32x4){0.f, 0.f, 0.f, 0.f};
    }

    const int sh = kg * 8;

    #pragma unroll 1
    for (int tq = 0; tq < 8; ++tq) {
        const u32x4 m0 = *reinterpret_cast<const u32x4*>(mrow0 + tq * 4);
        const u32x4 m1 = *reinterpret_cast<const u32x4*>(mrow1 + tq * 4);

        #pragma unroll
        for (int tw = 0; tw < 4; ++tw) {
            const int tn = tq * 4 + tw;
            const unsigned char* tb = tb0 + (size_t)tn * 4096;
            const s16x8 B0 = *reinterpret_cast<const s16x8*>(tb);
            const s16x8 B1 = *reinterpret_cast<const s16x8*>(tb + 1024);
            const s16x8 B2 = *reinterpret_cast<const s16x8*>(tb + 2048);
            const s16x8 B3 = *reinterpret_cast<const s16x8*>(tb + 3072);

            const int j0 = jq * 1024 + tn * 32 + kg * 8;
            const float4 q0 = *reinterpret_cast<const float4*>(&pqb[j0 * 2]);
            const float4 q1 = *reinterpret_cast<const float4*>(&pqb[j0 * 2 + 4]);
            const float4 q2 = *reinterpret_cast<const float4*>(&pqb[j0 * 2 + 8]);
            const float4 q3 = *reinterpret_cast<const float4*>(&pqb[j0 * 2 + 12]);

            const unsigned int mb0 = m0[tw] >> sh;
            const unsigned int mb1 = m1[tw] >> sh;

            s16x8 Af[2];
            #pragma unroll
            for (int s = 0; s < 2; ++s) {
                const float U = Us[s], V = Vs[s];
                const unsigned int mb = s ? mb1 : mb0;
                const float w0 = (mb & 1u)   ? fmaxf(U * q0.x, V * q0.y) : 0.f;
                const float w1 = (mb & 2u)   ? fmaxf(U * q0.z, V * q0.w) : 0.f;
                const float w2 = (mb & 4u)   ? fmaxf(U * q1.x, V * q1.y) : 0.f;
                const float w3 = (mb & 8u)   ? fmaxf(U * q1.z, V * q1.w) : 0.f;
                const float w4 = (mb & 16u)  ? fmaxf(U * q2.x, V * q2.y) : 0.f;
                const float w5 = (mb & 32u)  ? fmaxf(U * q2.z, V * q2.w) : 0.f;
                const float w6 = (mb & 64u)  ? fmaxf(U * q3.x, V * q3.y) : 0.f;
                const float w7 = (mb & 128u) ? fmaxf(U * q3.z, V * q3.w) : 0.f;
                u32x4 au;
                au.x = cvt_pk_bf16(w0, w1);
                au.y = cvt_pk_bf16(w2, w3);
                au.z = cvt_pk_bf16(w4, w5);
                au.w = cvt_pk_bf16(w6, w7);
                Af[s] = __builtin_bit_cast(s16x8, au);
            }

            #pragma unroll
            for (int s = 0; s < 2; ++s) {
                acc[s][0] = __builtin_amdgcn_mfma_f32_16x16x32_bf16(Af[s], B0, acc[s][0], 0, 0, 0);
                acc[s][1] = __builtin_amdgcn_mfma_f32_16x16x32_bf16(Af[s], B1, acc[s][1], 0, 0, 0);
                acc[s][2] = __builtin_amdgcn_mfma_f32_16x16x32_bf16(Af[s], B2, acc[s][2], 0, 0, 0);
                acc[s][3] = __builtin_amdgcn_mfma_f32_16x16x32_bf16(Af[s], B3, acc[s][3], 0, 0, 0);
                accZ[s]   = __builtin_amdgcn_mfma_f32_16x16x32_bf16(Af[s], ones, accZ[s], 0, 0, 0);
            }
        }
    }

    // ---- epilogue: combine 4 jq partials in LDS ----
    #pragma unroll 1
    for (int p = 0; p < 4; ++p) {
        if (jq == p) {
            #pragma unroll
            for (int s = 0; s < 2; ++s) {
                #pragma unroll
                for (int f = 0; f < 4; ++f) {
                    #pragma unroll
                    for (int rr = 0; rr < 4; ++rr) {
                        const int idx = (mloc * 32 + s * 16 + kg * 4 + rr) * 64 + f * 16 + col;
                        if (p == 0) accF[idx] = acc[s][f][rr];
                        else        accF[idx] += acc[s][f][rr];
                    }
                }
                if (col == 0) {
                    #pragma unroll
                    for (int rr = 0; rr < 4; ++rr) {
                        const int zi = mloc * 32 + s * 16 + kg * 4 + rr;
                        if (p == 0) zF[zi] = accZ[s][rr];
                        else        zF[zi] += accZ[s][rr];
                    }
                }
            }
        }
        __syncthreads();
    }

    // normalize + ELU + store: thread t handles 8 consecutive outputs
    const int f0    = t * 8;
    const int emloc = f0 >> 11;
    const int iloc  = (f0 >> 6) & 31;
    const int o0    = f0 & 63;
    const float inv = 1.0f / zF[emloc * 32 + iloc];
    const float* pa = &accF[f0];
    float res[8];
    #pragma unroll
    for (int e = 0; e < 8; ++e) {
        const float v = pa[e] * inv;
        res[e] = v > 0.f ? v : expm1f(v);
    }
    float* op = out + (size_t)(i0 + iloc) * 256 + (mp * 2 + emloc) * 64 + o0;
    *reinterpret_cast<float4*>(op)     = make_float4(res[0], res[1], res[2], res[3]);
    *reinterpret_cast<float4*>(op + 4) = make_float4(res[4], res[5], res[6], res[7]);
}

extern "C" void kernel_launch(void* const* d_in, const int* in_sizes, int n_in,
                              void* d_out, int out_size, void* d_ws, size_t ws_size,
                              hipStream_t stream) {
    const float* x   = (const float*)d_in[0];
    const int*   adj = (const int*)d_in[1];
    const float* W   = (const float*)d_in[2];
    const float* a1  = (const float*)d_in[3];
    const float* a2  = (const float*)d_in[4];
    const float* Wc  = (const float*)d_in[5];
    const float* bc  = (const float*)d_in[6];
    float* out = (float*)d_out;

    float* wsf    = (float*)d_ws;
    float* pooled = wsf;
    float* gbv    = wsf + 256;
    float* suv    = wsf + 768;
    float* spq    = wsf + 768 + 2 * MM * NN;
    unsigned char* htb = (unsigned char*)(wsf + 768 + 4 * MM * NN);
    unsigned long long* msk = (unsigned long long*)(htb + (size_t)NN * 512);

    (void)hipMemsetAsync(pooled, 0, INS_ * sizeof(float), stream);
    k_pack<<<1024, 256, 0, stream>>>(adj, msk);
    k_pool<<<256, 256, 0, stream>>>(x, pooled);
    k_cond<<<1, 512, 0, stream>>>(pooled, Wc, bc, gbv);
    k_film<<<dim3(128, 4), 256, 0, stream>>>(x, W, a1, a2, gbv, suv, spq, htb);
    k_attn<<<dim3(128, 2), 512, 0, stream>>>((const unsigned int*)msk, suv, spq, htb, out);
}

// Round 5
// 103.070 us; speedup vs baseline: 1.5954x; 1.2284x over previous
//
#include <hip/hip_runtime.h>
#include <hip/hip_bf16.h>

// Problem constants
#define NN    4096
#define INS_  256
#define OUTS_ 64
#define MM    4
#define LOG2E 1.4426950408889634f

typedef float f32x4 __attribute__((ext_vector_type(4)));
typedef short s16x8 __attribute__((ext_vector_type(8)));
typedef unsigned int u32x4 __attribute__((ext_vector_type(4)));

__device__ __forceinline__ unsigned int cvt_pk_bf16(float a, float b) {
    unsigned int r;
    asm("v_cvt_pk_bf16_f32 %0, %1, %2" : "=v"(r) : "v"(a), "v"(b));
    return r;
}

// pack two f32 into bf16x2 (RNE) - VALU fallback used in k_film (not hot)
__device__ __forceinline__ unsigned int pack_bf16(float a, float b) {
    unsigned int ua = __builtin_bit_cast(unsigned int, a);
    unsigned int ub = __builtin_bit_cast(unsigned int, b);
    ua = (ua + 0x7FFFu + ((ua >> 16) & 1u)) >> 16;
    ub = (ub + 0x7FFFu + ((ub >> 16) & 1u)) & 0xFFFF0000u;
    return ua | ub;
}

// keep w if bit e of mb set, else 0  (bfe_i32 sign-extend + and)
__device__ __forceinline__ float mand(float w, unsigned mb, int e) {
    const int m = ((int)(mb << (31 - e))) >> 31;
    return __builtin_bit_cast(float, (__builtin_bit_cast(int, w) & m));
}

// build A-fragment: 8 weights max(P, c*Q) masked, packed to bf16
__device__ __forceinline__ s16x8 mk_af(float c, unsigned mb,
        const f32x4 q0, const f32x4 q1, const f32x4 q2, const f32x4 q3) {
    const float w0 = mand(fmaxf(q0[0], c * q0[1]), mb, 0);
    const float w1 = mand(fmaxf(q0[2], c * q0[3]), mb, 1);
    const float w2 = mand(fmaxf(q1[0], c * q1[1]), mb, 2);
    const float w3 = mand(fmaxf(q1[2], c * q1[3]), mb, 3);
    const float w4 = mand(fmaxf(q2[0], c * q2[1]), mb, 4);
    const float w5 = mand(fmaxf(q2[2], c * q2[3]), mb, 5);
    const float w6 = mand(fmaxf(q3[0], c * q3[1]), mb, 6);
    const float w7 = mand(fmaxf(q3[2], c * q3[3]), mb, 7);
    u32x4 au;
    au.x = cvt_pk_bf16(w0, w1);
    au.y = cvt_pk_bf16(w2, w3);
    au.z = cvt_pk_bf16(w4, w5);
    au.w = cvt_pk_bf16(w6, w7);
    return __builtin_bit_cast(s16x8, au);
}

// ws layout (floats):
//   [0,256)        pooled
//   [256,768)      gb: gamma[4][64] then beta[4][64]
//   [768,+16384)   sc  float [M][N]   = V/U = 2^{-0.8 s'}
//   [+16384,+49152) spq float2[M][N]  = {2^{d'}, 2^{0.2 d'}}
//   then Ht bf16 tiles [m][jt=0..127][4KB]: tile(o,jj) at o*64+jj*2  (2 MB)
//   then adj bitmask [N][512B]                                      (2 MB)

// ---------- kernel 0: pack adjacency to bitmask (16-deep load bursts) ----------
__global__ __launch_bounds__(256) void k_pack(const int* __restrict__ adj,
                                              unsigned long long* __restrict__ msk) {
    const int lane = threadIdx.x & 63;
    const int w    = threadIdx.x >> 6;
    const int r    = blockIdx.x * 4 + w;
    const int* __restrict__ row = adj + (size_t)r * NN;
    unsigned long long* mrow = msk + (size_t)r * 64;
    #pragma unroll 1
    for (int c0 = 0; c0 < 64; c0 += 16) {
        int a[16];
        #pragma unroll
        for (int k = 0; k < 16; ++k) a[k] = row[(c0 + k) * 64 + lane];
        unsigned long long m[16];
        #pragma unroll
        for (int k = 0; k < 16; ++k) m[k] = __ballot(a[k] != 0);
        if (lane == 0) {
            #pragma unroll
            for (int k = 0; k < 16; ++k) mrow[c0 + k] = m[k];
        }
    }
}

// ---------- kernel 1a: column sums of x ----------
__global__ void k_pool(const float* __restrict__ x, float* __restrict__ pooled) {
    const int t = threadIdx.x;
    const int r0 = blockIdx.x * 16;
    float s = 0.f;
    #pragma unroll
    for (int r = 0; r < 16; ++r) s += x[(r0 + r) * INS_ + t];
    atomicAdd(&pooled[t], s);
}

// ---------- kernel 1b: gamma/beta ----------
__global__ void k_cond(const float* __restrict__ pooled, const float* __restrict__ Wc,
                       const float* __restrict__ bc, float* __restrict__ gb) {
    __shared__ float sp[INS_];
    const int t = threadIdx.x;          // 0..511
    if (t < INS_) sp[t] = pooled[t] * (1.0f / NN);
    __syncthreads();
    float acc = bc[t];
    #pragma unroll 4
    for (int i = 0; i < INS_; ++i) acc = fmaf(sp[i], Wc[i * 512 + t], acc);
    gb[t] = acc;
}

// ---------- kernel 2: h = FiLM(x@W); emit tiled Ht, sc, spq ----------
__global__ __launch_bounds__(256) void k_film(
    const float* __restrict__ x, const float* __restrict__ W,
    const float* __restrict__ a1, const float* __restrict__ a2,
    const float* __restrict__ gb, float* __restrict__ sc,
    float* __restrict__ spq, unsigned char* __restrict__ htb)
{
    const int t  = threadIdx.x;
    const int o  = t & 63;
    const int wv = __builtin_amdgcn_readfirstlane(t >> 6);   // wave 0..3
    const int m  = blockIdx.y;
    const int n0 = blockIdx.x * 32 + wv * 8;                 // this wave's 8 rows

    float acc[8];
    #pragma unroll
    for (int k = 0; k < 8; ++k) acc[k] = 0.f;

    const float* wp = W + (size_t)m * INS_ * OUTS_ + o;
    const float* xp = x + (size_t)n0 * INS_;

    #pragma unroll 4
    for (int i = 0; i < INS_; ++i) {
        const float wl = wp[(size_t)i * OUTS_];
        #pragma unroll
        for (int k = 0; k < 8; ++k)
            acc[k] = fmaf(xp[k * INS_ + i], wl, acc[k]);
    }

    const float ga  = gb[m * 64 + o];
    const float be  = gb[256 + m * 64 + o];
    const float va1 = a1[m * 64 + o];
    const float va2 = a2[m * 64 + o];

    float h[8], sv[8], dv[8];
    #pragma unroll
    for (int k = 0; k < 8; ++k) h[k] = fmaf(ga, acc[k], be);

    #pragma unroll
    for (int k = 0; k < 8; ++k) {
        float s1 = h[k] * va1;
        float s2 = h[k] * va2;
        #pragma unroll
        for (int off = 1; off < 64; off <<= 1) {
            s1 += __shfl_xor(s1, off);
            s2 += __shfl_xor(s2, off);
        }
        sv[k] = s1; dv[k] = s2;
    }

    // tile store: tile jt = blockIdx.x, rows jj = wv*8..wv*8+7
    u32x4 upk;
    upk.x = pack_bf16(h[0], h[1]);
    upk.y = pack_bf16(h[2], h[3]);
    upk.z = pack_bf16(h[4], h[5]);
    upk.w = pack_bf16(h[6], h[7]);
    const size_t phys = ((size_t)(m * 128 + blockIdx.x)) * 4096 + o * 64 + wv * 16;
    *reinterpret_cast<u32x4*>(htb + phys) = upk;

    // sc / spq
    const int lk = o & 7;
    float ssel = sv[0], dsel = dv[0];
    #pragma unroll
    for (int k = 1; k < 8; ++k) {
        if (lk == k) { ssel = sv[k]; dsel = dv[k]; }
    }
    if (o < 8) {
        sc[(size_t)m * NN + n0 + lk] = exp2f(-0.8f * LOG2E * ssel);
    } else if (o < 16) {
        const float spv = dsel * LOG2E;
        float2 ex = make_float2(exp2f(spv), exp2f(0.2f * spv));
        *reinterpret_cast<float2*>(&spq[(size_t)(m * NN + n0 + lk) * 2]) = ex;
    }
}

// ---------- kernel 3: fused masked softmax + PV ----------
// grid (128, 4): x = i-tile (32 rows), y = mech. 512 thr = 8 waves = 8 j-windows of 512.
// Each wave: 2 i-subtiles of 16, 16 tn iterations of 32 j, B-tile ping-pong prefetch.
#define LOADT(tn, B) do {                                                  \
    const unsigned char* tb_ = tb0 + (size_t)(tn) * 4096;                  \
    B[0] = *reinterpret_cast<const s16x8*>(tb_);                           \
    B[1] = *reinterpret_cast<const s16x8*>(tb_ + 1024);                    \
    B[2] = *reinterpret_cast<const s16x8*>(tb_ + 2048);                    \
    B[3] = *reinterpret_cast<const s16x8*>(tb_ + 3072);                    \
} while (0)

#define COMPUTE(tn, B, mw0, mw1) do {                                      \
    const float* qp_ = pqb + (tn) * 64;                                    \
    const f32x4 q0_ = *reinterpret_cast<const f32x4*>(qp_);                \
    const f32x4 q1_ = *reinterpret_cast<const f32x4*>(qp_ + 4);            \
    const f32x4 q2_ = *reinterpret_cast<const f32x4*>(qp_ + 8);            \
    const f32x4 q3_ = *reinterpret_cast<const f32x4*>(qp_ + 12);           \
    const s16x8 Af0_ = mk_af(c0v, (mw0) >> sh, q0_, q1_, q2_, q3_);        \
    const s16x8 Af1_ = mk_af(c1v, (mw1) >> sh, q0_, q1_, q2_, q3_);        \
    acc0[0] = __builtin_amdgcn_mfma_f32_16x16x32_bf16(Af0_, B[0], acc0[0], 0, 0, 0); \
    acc0[1] = __builtin_amdgcn_mfma_f32_16x16x32_bf16(Af0_, B[1], acc0[1], 0, 0, 0); \
    acc0[2] = __builtin_amdgcn_mfma_f32_16x16x32_bf16(Af0_, B[2], acc0[2], 0, 0, 0); \
    acc0[3] = __builtin_amdgcn_mfma_f32_16x16x32_bf16(Af0_, B[3], acc0[3], 0, 0, 0); \
    accZ0   = __builtin_amdgcn_mfma_f32_16x16x32_bf16(Af0_, ones, accZ0, 0, 0, 0);   \
    acc1[0] = __builtin_amdgcn_mfma_f32_16x16x32_bf16(Af1_, B[0], acc1[0], 0, 0, 0); \
    acc1[1] = __builtin_amdgcn_mfma_f32_16x16x32_bf16(Af1_, B[1], acc1[1], 0, 0, 0); \
    acc1[2] = __builtin_amdgcn_mfma_f32_16x16x32_bf16(Af1_, B[2], acc1[2], 0, 0, 0); \
    acc1[3] = __builtin_amdgcn_mfma_f32_16x16x32_bf16(Af1_, B[3], acc1[3], 0, 0, 0); \
    accZ1   = __builtin_amdgcn_mfma_f32_16x16x32_bf16(Af1_, ones, accZ1, 0, 0, 0);   \
} while (0)

__global__ __launch_bounds__(512, 2) void k_attn(
    const unsigned int* __restrict__ msk, const float* __restrict__ sc,
    const float* __restrict__ spq, const unsigned char* __restrict__ htb,
    float* __restrict__ out)
{
    extern __shared__ float lds[];           // accP[8][2048] + zP[8][32]
    float* accP = lds;
    float* zP   = lds + 8 * 2048;

    const int t    = threadIdx.x;
    const int lane = t & 63;
    const int jq   = __builtin_amdgcn_readfirstlane(t >> 6); // wave = j-window
    const int col  = lane & 15;
    const int kg   = lane >> 4;
    const int sh   = kg * 8;
    const int i0   = blockIdx.x * 32;
    const int mech = blockIdx.y;

    const float c0v = sc[(size_t)mech * NN + i0 + col];
    const float c1v = sc[(size_t)mech * NN + i0 + 16 + col];

    const u32x4* mr0 = reinterpret_cast<const u32x4*>(
        msk + (size_t)(i0 + col) * 128 + jq * 16);
    const u32x4* mr1 = reinterpret_cast<const u32x4*>(
        msk + (size_t)(i0 + 16 + col) * 128 + jq * 16);
    const float* pqb = spq + (size_t)mech * NN * 2 + (jq * 512 + kg * 8) * 2;
    const unsigned char* tb0 = htb + ((size_t)(mech * 128 + jq * 16)) * 4096
                             + col * 64 + kg * 16;

    const s16x8 ones = __builtin_bit_cast(s16x8,
        (u32x4){0x3F803F80u, 0x3F803F80u, 0x3F803F80u, 0x3F803F80u});

    f32x4 acc0[4], acc1[4], accZ0, accZ1;
    accZ0 = (f32x4){0.f, 0.f, 0.f, 0.f};
    accZ1 = accZ0;
    #pragma unroll
    for (int f = 0; f < 4; ++f) { acc0[f] = accZ0; acc1[f] = accZ0; }

    s16x8 Ba[4], Bb[4];
    LOADT(0, Ba);
    u32x4 m0n = mr0[0];
    u32x4 m1n = mr1[0];

    #pragma unroll 1
    for (int tq = 0; tq < 4; ++tq) {
        const int base = tq * 4;
        const u32x4 m0 = m0n, m1 = m1n;
        if (tq < 3) { m0n = mr0[tq + 1]; m1n = mr1[tq + 1]; }
        LOADT(base + 1, Bb);
        COMPUTE(base + 0, Ba, m0[0], m1[0]);
        LOADT(base + 2, Ba);
        COMPUTE(base + 1, Bb, m0[1], m1[1]);
        LOADT(base + 3, Bb);
        COMPUTE(base + 2, Ba, m0[2], m1[2]);
        if (tq < 3) LOADT(base + 4, Ba);
        COMPUTE(base + 3, Bb, m0[3], m1[3]);
    }

    // ---- epilogue: each wave writes its 8KB partial; parallel 8-way reduce ----
    float* my = accP + jq * 2048;
    #pragma unroll
    for (int f = 0; f < 4; ++f) {
        #pragma unroll
        for (int rr = 0; rr < 4; ++rr) {
            my[(kg * 4 + rr) * 64 + f * 16 + col]      = acc0[f][rr];
            my[(16 + kg * 4 + rr) * 64 + f * 16 + col] = acc1[f][rr];
        }
    }
    if (col == 0) {
        #pragma unroll
        for (int rr = 0; rr < 4; ++rr) {
            zP[jq * 32 + kg * 4 + rr]      = accZ0[rr];
            zP[jq * 32 + 16 + kg * 4 + rr] = accZ1[rr];
        }
    }
    __syncthreads();

    const int row = t >> 4;            // 0..31
    const int o0  = (t & 15) * 4;      // 0..60
    f32x4 s = (f32x4){0.f, 0.f, 0.f, 0.f};
    float z = 0.f;
    #pragma unroll
    for (int p = 0; p < 8; ++p) {
        s += *reinterpret_cast<const f32x4*>(accP + p * 2048 + row * 64 + o0);
        z += zP[p * 32 + row];
    }
    const float inv = 1.0f / z;
    f32x4 res;
    #pragma unroll
    for (int e = 0; e < 4; ++e) {
        const float v = s[e] * inv;
        res[e] = v > 0.f ? v : expm1f(v);
    }
    *reinterpret_cast<f32x4*>(out + (size_t)(i0 + row) * 256 + mech * 64 + o0) = res;
}

extern "C" void kernel_launch(void* const* d_in, const int* in_sizes, int n_in,
                              void* d_out, int out_size, void* d_ws, size_t ws_size,
                              hipStream_t stream) {
    const float* x   = (const float*)d_in[0];
    const int*   adj = (const int*)d_in[1];
    const float* W   = (const float*)d_in[2];
    const float* a1  = (const float*)d_in[3];
    const float* a2  = (const float*)d_in[4];
    const float* Wc  = (const float*)d_in[5];
    const float* bc  = (const float*)d_in[6];
    float* out = (float*)d_out;

    float* wsf    = (float*)d_ws;
    float* pooled = wsf;
    float* gbv    = wsf + 256;
    float* scv    = wsf + 768;
    float* spq    = wsf + 768 + MM * NN;
    unsigned char* htb = (unsigned char*)(wsf + 768 + 3 * MM * NN);
    unsigned long long* msk = (unsigned long long*)(htb + (size_t)2097152);

    (void)hipFuncSetAttribute((const void*)k_attn,
                              hipFuncAttributeMaxDynamicSharedMemorySize, 66560);

    (void)hipMemsetAsync(pooled, 0, INS_ * sizeof(float), stream);
    k_pack<<<1024, 256, 0, stream>>>(adj, msk);
    k_pool<<<256, 256, 0, stream>>>(x, pooled);
    k_cond<<<1, 512, 0, stream>>>(pooled, Wc, bc, gbv);
    k_film<<<dim3(128, 4), 256, 0, stream>>>(x, W, a1, a2, gbv, scv, spq, htb);
    k_attn<<<dim3(128, 4), 512, 66560, stream>>>((const unsigned int*)msk, scv, spq, htb, out);
}

// Round 6
// 94.801 us; speedup vs baseline: 1.7345x; 1.0872x over previous
//
#include <hip/hip_runtime.h>
#include <hip/hip_bf16.h>

// Problem constants
#define NN    4096
#define INS_  256
#define OUTS_ 64
#define MM    4
#define LOG2E 1.4426950408889634f

typedef float f32x4 __attribute__((ext_vector_type(4)));
typedef short s16x8 __attribute__((ext_vector_type(8)));
typedef unsigned int u32x4 __attribute__((ext_vector_type(4)));

__device__ __forceinline__ unsigned int cvt_pk_bf16(float a, float b) {
    unsigned int r;
    asm("v_cvt_pk_bf16_f32 %0, %1, %2" : "=v"(r) : "v"(a), "v"(b));
    return r;
}

// pack two f32 into bf16x2 (RNE) - VALU fallback used in k_film (not hot)
__device__ __forceinline__ unsigned int pack_bf16(float a, float b) {
    unsigned int ua = __builtin_bit_cast(unsigned int, a);
    unsigned int ub = __builtin_bit_cast(unsigned int, b);
    ua = (ua + 0x7FFFu + ((ua >> 16) & 1u)) >> 16;
    ub = (ub + 0x7FFFu + ((ub >> 16) & 1u)) & 0xFFFF0000u;
    return ua | ub;
}

// keep w if bit e of mb set, else 0  (sign-extend bit + and)
__device__ __forceinline__ float mand(float w, unsigned mb, int e) {
    const int m = ((int)(mb << (31 - e))) >> 31;
    return __builtin_bit_cast(float, (__builtin_bit_cast(int, w) & m));
}

// build A-fragment: 8 weights max(P, c*Q) masked, packed to bf16
__device__ __forceinline__ s16x8 mk_af(float c, unsigned mb,
        const f32x4 q0, const f32x4 q1, const f32x4 q2, const f32x4 q3) {
    const float w0 = mand(fmaxf(q0[0], c * q0[1]), mb, 0);
    const float w1 = mand(fmaxf(q0[2], c * q0[3]), mb, 1);
    const float w2 = mand(fmaxf(q1[0], c * q1[1]), mb, 2);
    const float w3 = mand(fmaxf(q1[2], c * q1[3]), mb, 3);
    const float w4 = mand(fmaxf(q2[0], c * q2[1]), mb, 4);
    const float w5 = mand(fmaxf(q2[2], c * q2[3]), mb, 5);
    const float w6 = mand(fmaxf(q3[0], c * q3[1]), mb, 6);
    const float w7 = mand(fmaxf(q3[2], c * q3[3]), mb, 7);
    u32x4 au;
    au.x = cvt_pk_bf16(w0, w1);
    au.y = cvt_pk_bf16(w2, w3);
    au.z = cvt_pk_bf16(w4, w5);
    au.w = cvt_pk_bf16(w6, w7);
    return __builtin_bit_cast(s16x8, au);
}

// ws layout (floats):
//   [0,16384)       part float [64][256]  (k_pool partial column sums)
//   [16384,16896)   gb: gamma[4][64] then beta[4][64]
//   [16896,33280)   sc  float [M][N]   = V/U = 2^{-0.8 s'}
//   [33280,66048)   spq float2[M][N]   = {2^{d'}, 2^{0.2 d'}}
//   byte 264192     Ht bf16 tiles [m][jt=0..127][4KB]: tile(o,jj) at o*64+jj*2  (2 MB)
//   byte 2361344    adj bitmask [N][512B]                                       (2 MB)

// ---------- kernel 0: pack adjacency to bitmask (16-deep load bursts) ----------
__global__ __launch_bounds__(256) void k_pack(const int* __restrict__ adj,
                                              unsigned long long* __restrict__ msk) {
    const int lane = threadIdx.x & 63;
    const int w    = threadIdx.x >> 6;
    const int r    = blockIdx.x * 4 + w;
    const int* __restrict__ row = adj + (size_t)r * NN;
    unsigned long long* mrow = msk + (size_t)r * 64;
    #pragma unroll 1
    for (int c0 = 0; c0 < 64; c0 += 16) {
        int a[16];
        #pragma unroll
        for (int k = 0; k < 16; ++k) a[k] = row[(c0 + k) * 64 + lane];
        unsigned long long m[16];
        #pragma unroll
        for (int k = 0; k < 16; ++k) m[k] = __ballot(a[k] != 0);
        if (lane == 0) {
            #pragma unroll
            for (int k = 0; k < 16; ++k) mrow[c0 + k] = m[k];
        }
    }
}

// ---------- kernel 1a: partial column sums of x (no atomics, no memset) ----------
__global__ __launch_bounds__(256) void k_pool(const float* __restrict__ x,
                                              float* __restrict__ part) {
    const int t = threadIdx.x;
    const int r0 = blockIdx.x * 64;
    float s = 0.f;
    #pragma unroll 8
    for (int r = 0; r < 64; ++r) s += x[(size_t)(r0 + r) * INS_ + t];
    part[blockIdx.x * INS_ + t] = s;
}

// ---------- kernel 1b: reduce partials; gamma/beta ----------
__global__ void k_cond(const float* __restrict__ part, const float* __restrict__ Wc,
                       const float* __restrict__ bc, float* __restrict__ gb) {
    __shared__ float sp[INS_];
    const int t = threadIdx.x;          // 0..511
    if (t < INS_) {
        float s = 0.f;
        #pragma unroll 8
        for (int b = 0; b < 64; ++b) s += part[b * INS_ + t];
        sp[t] = s * (1.0f / NN);
    }
    __syncthreads();
    float acc = bc[t];
    #pragma unroll 4
    for (int i = 0; i < INS_; ++i) acc = fmaf(sp[i], Wc[i * 512 + t], acc);
    gb[t] = acc;
}

// ---------- kernel 2: h = FiLM(x@W); emit tiled Ht, sc, spq ----------
__global__ __launch_bounds__(256) void k_film(
    const float* __restrict__ x, const float* __restrict__ W,
    const float* __restrict__ a1, const float* __restrict__ a2,
    const float* __restrict__ gb, float* __restrict__ sc,
    float* __restrict__ spq, unsigned char* __restrict__ htb)
{
    const int t  = threadIdx.x;
    const int o  = t & 63;
    const int wv = __builtin_amdgcn_readfirstlane(t >> 6);   // wave 0..3
    const int m  = blockIdx.y;
    const int n0 = blockIdx.x * 32 + wv * 8;                 // this wave's 8 rows

    float acc[8];
    #pragma unroll
    for (int k = 0; k < 8; ++k) acc[k] = 0.f;

    const float* wp = W + (size_t)m * INS_ * OUTS_ + o;
    const float* xp = x + (size_t)n0 * INS_;

    #pragma unroll 4
    for (int i = 0; i < INS_; ++i) {
        const float wl = wp[(size_t)i * OUTS_];
        #pragma unroll
        for (int k = 0; k < 8; ++k)
            acc[k] = fmaf(xp[k * INS_ + i], wl, acc[k]);
    }

    const float ga  = gb[m * 64 + o];
    const float be  = gb[256 + m * 64 + o];
    const float va1 = a1[m * 64 + o];
    const float va2 = a2[m * 64 + o];

    float h[8], sv[8], dv[8];
    #pragma unroll
    for (int k = 0; k < 8; ++k) h[k] = fmaf(ga, acc[k], be);

    #pragma unroll
    for (int k = 0; k < 8; ++k) {
        float s1 = h[k] * va1;
        float s2 = h[k] * va2;
        #pragma unroll
        for (int off = 1; off < 64; off <<= 1) {
            s1 += __shfl_xor(s1, off);
            s2 += __shfl_xor(s2, off);
        }
        sv[k] = s1; dv[k] = s2;
    }

    // tile store: tile jt = blockIdx.x, rows jj = wv*8..wv*8+7
    u32x4 upk;
    upk.x = pack_bf16(h[0], h[1]);
    upk.y = pack_bf16(h[2], h[3]);
    upk.z = pack_bf16(h[4], h[5]);
    upk.w = pack_bf16(h[6], h[7]);
    const size_t phys = ((size_t)(m * 128 + blockIdx.x)) * 4096 + o * 64 + wv * 16;
    *reinterpret_cast<u32x4*>(htb + phys) = upk;

    // sc / spq
    const int lk = o & 7;
    float ssel = sv[0], dsel = dv[0];
    #pragma unroll
    for (int k = 1; k < 8; ++k) {
        if (lk == k) { ssel = sv[k]; dsel = dv[k]; }
    }
    if (o < 8) {
        sc[(size_t)m * NN + n0 + lk] = exp2f(-0.8f * LOG2E * ssel);
    } else if (o < 16) {
        const float spv = dsel * LOG2E;
        float2 ex = make_float2(exp2f(spv), exp2f(0.2f * spv));
        *reinterpret_cast<float2*>(&spq[(size_t)(m * NN + n0 + lk) * 2]) = ex;
    }
}

// ---------- kernel 3: fused masked softmax + PV ----------
// grid (128, 4): x = i-tile (32 rows), y = mech. 512 thr = 8 waves = 8 j-windows of 512.
// Each wave: 2 i-subtiles of 16, 16 tn iterations of 32 j, B-tile ping-pong prefetch.
#define LOADT(tn, B) do {                                                  \
    const unsigned char* tb_ = tb0 + (size_t)(tn) * 4096;                  \
    B[0] = *reinterpret_cast<const s16x8*>(tb_);                           \
    B[1] = *reinterpret_cast<const s16x8*>(tb_ + 1024);                    \
    B[2] = *reinterpret_cast<const s16x8*>(tb_ + 2048);                    \
    B[3] = *reinterpret_cast<const s16x8*>(tb_ + 3072);                    \
} while (0)

#define COMPUTE(tn, B, mw0, mw1) do {                                      \
    const float* qp_ = pqb + (tn) * 64;                                    \
    const f32x4 q0_ = *reinterpret_cast<const f32x4*>(qp_);                \
    const f32x4 q1_ = *reinterpret_cast<const f32x4*>(qp_ + 4);            \
    const f32x4 q2_ = *reinterpret_cast<const f32x4*>(qp_ + 8);            \
    const f32x4 q3_ = *reinterpret_cast<const f32x4*>(qp_ + 12);           \
    const s16x8 Af0_ = mk_af(c0v, (mw0) >> sh, q0_, q1_, q2_, q3_);        \
    const s16x8 Af1_ = mk_af(c1v, (mw1) >> sh, q0_, q1_, q2_, q3_);        \
    acc0[0] = __builtin_amdgcn_mfma_f32_16x16x32_bf16(Af0_, B[0], acc0[0], 0, 0, 0); \
    acc0[1] = __builtin_amdgcn_mfma_f32_16x16x32_bf16(Af0_, B[1], acc0[1], 0, 0, 0); \
    acc0[2] = __builtin_amdgcn_mfma_f32_16x16x32_bf16(Af0_, B[2], acc0[2], 0, 0, 0); \
    acc0[3] = __builtin_amdgcn_mfma_f32_16x16x32_bf16(Af0_, B[3], acc0[3], 0, 0, 0); \
    accZ0   = __builtin_amdgcn_mfma_f32_16x16x32_bf16(Af0_, ones, accZ0, 0, 0, 0);   \
    acc1[0] = __builtin_amdgcn_mfma_f32_16x16x32_bf16(Af1_, B[0], acc1[0], 0, 0, 0); \
    acc1[1] = __builtin_amdgcn_mfma_f32_16x16x32_bf16(Af1_, B[1], acc1[1], 0, 0, 0); \
    acc1[2] = __builtin_amdgcn_mfma_f32_16x16x32_bf16(Af1_, B[2], acc1[2], 0, 0, 0); \
    acc1[3] = __builtin_amdgcn_mfma_f32_16x16x32_bf16(Af1_, B[3], acc1[3], 0, 0, 0); \
    accZ1   = __builtin_amdgcn_mfma_f32_16x16x32_bf16(Af1_, ones, accZ1, 0, 0, 0);   \
} while (0)

__global__ __launch_bounds__(512, 2) void k_attn(
    const unsigned int* __restrict__ msk, const float* __restrict__ sc,
    const float* __restrict__ spq, const unsigned char* __restrict__ htb,
    float* __restrict__ out)
{
    extern __shared__ float lds[];           // accP[8][2048] + zP[8][32]
    float* accP = lds;
    float* zP   = lds + 8 * 2048;

    const int t    = threadIdx.x;
    const int lane = t & 63;
    const int jq   = __builtin_amdgcn_readfirstlane(t >> 6); // wave = j-window
    const int col  = lane & 15;
    const int kg   = lane >> 4;
    const int sh   = kg * 8;
    const int i0   = blockIdx.x * 32;
    const int mech = blockIdx.y;

    const float c0v = sc[(size_t)mech * NN + i0 + col];
    const float c1v = sc[(size_t)mech * NN + i0 + 16 + col];

    const u32x4* mr0 = reinterpret_cast<const u32x4*>(
        msk + (size_t)(i0 + col) * 128 + jq * 16);
    const u32x4* mr1 = reinterpret_cast<const u32x4*>(
        msk + (size_t)(i0 + 16 + col) * 128 + jq * 16);
    const float* pqb = spq + (size_t)mech * NN * 2 + (jq * 512 + kg * 8) * 2;
    const unsigned char* tb0 = htb + ((size_t)(mech * 128 + jq * 16)) * 4096
                             + col * 64 + kg * 16;

    const s16x8 ones = __builtin_bit_cast(s16x8,
        (u32x4){0x3F803F80u, 0x3F803F80u, 0x3F803F80u, 0x3F803F80u});

    f32x4 acc0[4], acc1[4], accZ0, accZ1;
    accZ0 = (f32x4){0.f, 0.f, 0.f, 0.f};
    accZ1 = accZ0;
    #pragma unroll
    for (int f = 0; f < 4; ++f) { acc0[f] = accZ0; acc1[f] = accZ0; }

    s16x8 Ba[4], Bb[4];
    LOADT(0, Ba);
    u32x4 m0n = mr0[0];
    u32x4 m1n = mr1[0];

    #pragma unroll 1
    for (int tq = 0; tq < 4; ++tq) {
        const int base = tq * 4;
        const u32x4 m0 = m0n, m1 = m1n;
        if (tq < 3) { m0n = mr0[tq + 1]; m1n = mr1[tq + 1]; }
        LOADT(base + 1, Bb);
        COMPUTE(base + 0, Ba, m0[0], m1[0]);
        LOADT(base + 2, Ba);
        COMPUTE(base + 1, Bb, m0[1], m1[1]);
        LOADT(base + 3, Bb);
        COMPUTE(base + 2, Ba, m0[2], m1[2]);
        if (tq < 3) LOADT(base + 4, Ba);
        COMPUTE(base + 3, Bb, m0[3], m1[3]);
    }

    // ---- epilogue: each wave writes its 8KB partial; parallel 8-way reduce ----
    float* my = accP + jq * 2048;
    #pragma unroll
    for (int f = 0; f < 4; ++f) {
        #pragma unroll
        for (int rr = 0; rr < 4; ++rr) {
            my[(kg * 4 + rr) * 64 + f * 16 + col]      = acc0[f][rr];
            my[(16 + kg * 4 + rr) * 64 + f * 16 + col] = acc1[f][rr];
        }
    }
    if (col == 0) {
        #pragma unroll
        for (int rr = 0; rr < 4; ++rr) {
            zP[jq * 32 + kg * 4 + rr]      = accZ0[rr];
            zP[jq * 32 + 16 + kg * 4 + rr] = accZ1[rr];
        }
    }
    __syncthreads();

    const int row = t >> 4;            // 0..31
    const int o0  = (t & 15) * 4;      // 0..60
    f32x4 s = (f32x4){0.f, 0.f, 0.f, 0.f};
    float z = 0.f;
    #pragma unroll
    for (int p = 0; p < 8; ++p) {
        s += *reinterpret_cast<const f32x4*>(accP + p * 2048 + row * 64 + o0);
        z += zP[p * 32 + row];
    }
    const float inv = 1.0f / z;
    f32x4 res;
    #pragma unroll
    for (int e = 0; e < 4; ++e) {
        const float v = s[e] * inv;
        res[e] = v > 0.f ? v : expm1f(v);
    }
    *reinterpret_cast<f32x4*>(out + (size_t)(i0 + row) * 256 + mech * 64 + o0) = res;
}

extern "C" void kernel_launch(void* const* d_in, const int* in_sizes, int n_in,
                              void* d_out, int out_size, void* d_ws, size_t ws_size,
                              hipStream_t stream) {
    const float* x   = (const float*)d_in[0];
    const int*   adj = (const int*)d_in[1];
    const float* W   = (const float*)d_in[2];
    const float* a1  = (const float*)d_in[3];
    const float* a2  = (const float*)d_in[4];
    const float* Wc  = (const float*)d_in[5];
    const float* bc  = (const float*)d_in[6];
    float* out = (float*)d_out;

    float* wsf    = (float*)d_ws;
    float* part   = wsf;
    float* gbv    = wsf + 16384;
    float* scv    = wsf + 16896;
    float* spq    = wsf + 33280;
    unsigned char* htb = (unsigned char*)(wsf + 66048);
    unsigned long long* msk = (unsigned long long*)(htb + (size_t)2097152);

    (void)hipFuncSetAttribute((const void*)k_attn,
                              hipFuncAttributeMaxDynamicSharedMemorySize, 66560);

    k_pack<<<1024, 256, 0, stream>>>(adj, msk);
    k_pool<<<64, 256, 0, stream>>>(x, part);
    k_cond<<<1, 512, 0, stream>>>(part, Wc, bc, gbv);
    k_film<<<dim3(128, 4), 256, 0, stream>>>(x, W, a1, a2, gbv, scv, spq, htb);
    k_attn<<<dim3(128, 4), 512, 66560, stream>>>((const unsigned int*)msk, scv, spq, htb, out);
}

// Round 7
// 93.518 us; speedup vs baseline: 1.7583x; 1.0137x over previous
//
#include <hip/hip_runtime.h>
#include <hip/hip_bf16.h>

// Problem constants
#define NN    4096
#define INS_  256
#define OUTS_ 64
#define MM    4
#define LOG2E 1.4426950408889634f

typedef float f32x4 __attribute__((ext_vector_type(4)));
typedef short s16x8 __attribute__((ext_vector_type(8)));
typedef unsigned int u32x4 __attribute__((ext_vector_type(4)));

__device__ __forceinline__ unsigned int cvt_pk_bf16(float a, float b) {
    unsigned int r;
    asm("v_cvt_pk_bf16_f32 %0, %1, %2" : "=v"(r) : "v"(a), "v"(b));
    return r;
}

// pack two f32 into bf16x2 (RNE) - VALU fallback used in k_filmc (not hot)
__device__ __forceinline__ unsigned int pack_bf16(float a, float b) {
    unsigned int ua = __builtin_bit_cast(unsigned int, a);
    unsigned int ub = __builtin_bit_cast(unsigned int, b);
    ua = (ua + 0x7FFFu + ((ua >> 16) & 1u)) >> 16;
    ub = (ub + 0x7FFFu + ((ub >> 16) & 1u)) & 0xFFFF0000u;
    return ua | ub;
}

// keep w if bit e of mb set, else 0  (sign-extend bit + and)
__device__ __forceinline__ float mand(float w, unsigned mb, int e) {
    const int m = ((int)(mb << (31 - e))) >> 31;
    return __builtin_bit_cast(float, (__builtin_bit_cast(int, w) & m));
}

// build A-fragment: 8 weights max(P, c*Q) masked, packed to bf16; accumulate f32 Z
__device__ __forceinline__ s16x8 mk_af(float c, unsigned mb,
        const f32x4 q0, const f32x4 q1, const f32x4 q2, const f32x4 q3, float& z) {
    const float w0 = mand(fmaxf(q0[0], c * q0[1]), mb, 0);
    const float w1 = mand(fmaxf(q0[2], c * q0[3]), mb, 1);
    const float w2 = mand(fmaxf(q1[0], c * q1[1]), mb, 2);
    const float w3 = mand(fmaxf(q1[2], c * q1[3]), mb, 3);
    const float w4 = mand(fmaxf(q2[0], c * q2[1]), mb, 4);
    const float w5 = mand(fmaxf(q2[2], c * q2[3]), mb, 5);
    const float w6 = mand(fmaxf(q3[0], c * q3[1]), mb, 6);
    const float w7 = mand(fmaxf(q3[2], c * q3[3]), mb, 7);
    z += ((w0 + w1) + (w2 + w3)) + ((w4 + w5) + (w6 + w7));
    u32x4 au;
    au.x = cvt_pk_bf16(w0, w1);
    au.y = cvt_pk_bf16(w2, w3);
    au.z = cvt_pk_bf16(w4, w5);
    au.w = cvt_pk_bf16(w6, w7);
    return __builtin_bit_cast(s16x8, au);
}

// ws layout (floats):
//   [0,16384)       part float [64][256]  (partial column sums)
//   [16384,16896)   (unused)
//   [16896,33280)   sc  float [M][N]   = V/U = 2^{-0.8 s'}
//   [33280,66048)   spq float2[M][N]   = {2^{d'}, 2^{0.2 d'}}
//   byte 264192     Ht bf16 tiles [m][jt=0..127][4KB]: tile(o,jj) at o*64+jj*2  (2 MB)
//   byte 2361344    adj bitmask [N][512B]                                       (2 MB)

// ---------- kernel 1: fused adj->bitmask pack (blocks 0..1023) + x column
//            partial sums (blocks 1024..1087) ----------
__global__ __launch_bounds__(256) void k_prep(const int* __restrict__ adj,
                                              unsigned long long* __restrict__ msk,
                                              const float* __restrict__ x,
                                              float* __restrict__ part) {
    const int b = blockIdx.x;
    if (b < 1024) {
        const int lane = threadIdx.x & 63;
        const int w    = threadIdx.x >> 6;
        const int r    = b * 4 + w;
        const int* __restrict__ row = adj + (size_t)r * NN;
        unsigned long long* mrow = msk + (size_t)r * 64;
        #pragma unroll 1
        for (int c0 = 0; c0 < 64; c0 += 16) {
            int a[16];
            #pragma unroll
            for (int k = 0; k < 16; ++k) a[k] = row[(c0 + k) * 64 + lane];
            unsigned long long m[16];
            #pragma unroll
            for (int k = 0; k < 16; ++k) m[k] = __ballot(a[k] != 0);
            if (lane == 0) {
                #pragma unroll
                for (int k = 0; k < 16; ++k) mrow[c0 + k] = m[k];
            }
        }
    } else {
        const int bb = b - 1024;
        const int t  = threadIdx.x;
        const int r0 = bb * 64;
        float s = 0.f;
        #pragma unroll 8
        for (int r = 0; r < 64; ++r) s += x[(size_t)(r0 + r) * INS_ + t];
        part[bb * INS_ + t] = s;
    }
}

// ---------- kernel 2: fused conditioner + FiLM; emit tiled Ht, sc, spq ----------
__global__ __launch_bounds__(256) void k_filmc(
    const float* __restrict__ x, const float* __restrict__ W,
    const float* __restrict__ a1, const float* __restrict__ a2,
    const float* __restrict__ part, const float* __restrict__ Wc,
    const float* __restrict__ bc, float* __restrict__ sc,
    float* __restrict__ spq, unsigned char* __restrict__ htb)
{
    __shared__ float sp[INS_];
    __shared__ float gg[64], bbv[64];

    const int t  = threadIdx.x;
    const int o  = t & 63;
    const int wv = __builtin_amdgcn_readfirstlane(t >> 6);   // wave 0..3
    const int m  = blockIdx.y;
    const int n0 = blockIdx.x * 32 + wv * 8;                 // this wave's 8 rows

    // conditioner prologue: reduce partials, compute this mech's gamma/beta
    {
        float s = 0.f;
        #pragma unroll 8
        for (int b = 0; b < 64; ++b) s += part[b * INS_ + t];
        sp[t] = s * (1.0f / NN);
    }
    __syncthreads();
    if (t < 128) {
        const int col = m * 64 + (t & 63) + ((t < 64) ? 0 : 256);
        float acc = bc[col];
        #pragma unroll 4
        for (int i = 0; i < INS_; ++i) acc = fmaf(sp[i], Wc[i * 512 + col], acc);
        if (t < 64) gg[t] = acc; else bbv[t - 64] = acc;
    }
    __syncthreads();

    float acc[8];
    #pragma unroll
    for (int k = 0; k < 8; ++k) acc[k] = 0.f;

    const float* wp = W + (size_t)m * INS_ * OUTS_ + o;
    const float* xp = x + (size_t)n0 * INS_;

    #pragma unroll 4
    for (int i = 0; i < INS_; ++i) {
        const float wl = wp[(size_t)i * OUTS_];
        #pragma unroll
        for (int k = 0; k < 8; ++k)
            acc[k] = fmaf(xp[k * INS_ + i], wl, acc[k]);
    }

    const float ga  = gg[o];
    const float be  = bbv[o];
    const float va1 = a1[m * 64 + o];
    const float va2 = a2[m * 64 + o];

    float h[8], sv[8], dv[8];
    #pragma unroll
    for (int k = 0; k < 8; ++k) h[k] = fmaf(ga, acc[k], be);

    #pragma unroll
    for (int k = 0; k < 8; ++k) {
        float s1 = h[k] * va1;
        float s2 = h[k] * va2;
        #pragma unroll
        for (int off = 1; off < 64; off <<= 1) {
            s1 += __shfl_xor(s1, off);
            s2 += __shfl_xor(s2, off);
        }
        sv[k] = s1; dv[k] = s2;
    }

    // tile store: tile jt = blockIdx.x, rows jj = wv*8..wv*8+7
    u32x4 upk;
    upk.x = pack_bf16(h[0], h[1]);
    upk.y = pack_bf16(h[2], h[3]);
    upk.z = pack_bf16(h[4], h[5]);
    upk.w = pack_bf16(h[6], h[7]);
    const size_t phys = ((size_t)(m * 128 + blockIdx.x)) * 4096 + o * 64 + wv * 16;
    *reinterpret_cast<u32x4*>(htb + phys) = upk;

    // sc / spq
    const int lk = o & 7;
    float ssel = sv[0], dsel = dv[0];
    #pragma unroll
    for (int k = 1; k < 8; ++k) {
        if (lk == k) { ssel = sv[k]; dsel = dv[k]; }
    }
    if (o < 8) {
        sc[(size_t)m * NN + n0 + lk] = exp2f(-0.8f * LOG2E * ssel);
    } else if (o < 16) {
        const float spv = dsel * LOG2E;
        float2 ex = make_float2(exp2f(spv), exp2f(0.2f * spv));
        *reinterpret_cast<float2*>(&spq[(size_t)(m * NN + n0 + lk) * 2]) = ex;
    }
}

// ---------- kernel 3: fused masked softmax + PV ----------
// grid (128, 4): x = i-tile (32 rows), y = mech. 512 thr = 8 waves = 8 j-windows of 512.
// Each wave: 2 i-subtiles of 16, 16 tn iterations of 32 j, B+Q ping-pong prefetch.
#define LOADT(tn, B) do {                                                  \
    const unsigned char* tb_ = tb0 + (size_t)(tn) * 4096;                  \
    B[0] = *reinterpret_cast<const s16x8*>(tb_);                           \
    B[1] = *reinterpret_cast<const s16x8*>(tb_ + 1024);                    \
    B[2] = *reinterpret_cast<const s16x8*>(tb_ + 2048);                    \
    B[3] = *reinterpret_cast<const s16x8*>(tb_ + 3072);                    \
} while (0)

#define QLOAD(tn, Q) do {                                                  \
    const float* qp_ = pqb + (tn) * 64;                                    \
    Q[0] = *reinterpret_cast<const f32x4*>(qp_);                           \
    Q[1] = *reinterpret_cast<const f32x4*>(qp_ + 4);                       \
    Q[2] = *reinterpret_cast<const f32x4*>(qp_ + 8);                       \
    Q[3] = *reinterpret_cast<const f32x4*>(qp_ + 12);                      \
} while (0)

#define COMPUTE(B, Q, mw0, mw1) do {                                       \
    const s16x8 Af0_ = mk_af(c0v, (mw0) >> sh, Q[0], Q[1], Q[2], Q[3], z0);\
    const s16x8 Af1_ = mk_af(c1v, (mw1) >> sh, Q[0], Q[1], Q[2], Q[3], z1);\
    acc0[0] = __builtin_amdgcn_mfma_f32_16x16x32_bf16(Af0_, B[0], acc0[0], 0, 0, 0); \
    acc0[1] = __builtin_amdgcn_mfma_f32_16x16x32_bf16(Af0_, B[1], acc0[1], 0, 0, 0); \
    acc0[2] = __builtin_amdgcn_mfma_f32_16x16x32_bf16(Af0_, B[2], acc0[2], 0, 0, 0); \
    acc0[3] = __builtin_amdgcn_mfma_f32_16x16x32_bf16(Af0_, B[3], acc0[3], 0, 0, 0); \
    acc1[0] = __builtin_amdgcn_mfma_f32_16x16x32_bf16(Af1_, B[0], acc1[0], 0, 0, 0); \
    acc1[1] = __builtin_amdgcn_mfma_f32_16x16x32_bf16(Af1_, B[1], acc1[1], 0, 0, 0); \
    acc1[2] = __builtin_amdgcn_mfma_f32_16x16x32_bf16(Af1_, B[2], acc1[2], 0, 0, 0); \
    acc1[3] = __builtin_amdgcn_mfma_f32_16x16x32_bf16(Af1_, B[3], acc1[3], 0, 0, 0); \
} while (0)

__global__ __launch_bounds__(512, 2) void k_attn(
    const unsigned int* __restrict__ msk, const float* __restrict__ sc,
    const float* __restrict__ spq, const unsigned char* __restrict__ htb,
    float* __restrict__ out)
{
    extern __shared__ float lds[];           // accP[8][2048] + zP[8][32]
    float* accP = lds;
    float* zP   = lds + 8 * 2048;

    const int t    = threadIdx.x;
    const int lane = t & 63;
    const int jq   = __builtin_amdgcn_readfirstlane(t >> 6); // wave = j-window
    const int col  = lane & 15;
    const int kg   = lane >> 4;
    const int sh   = kg * 8;
    const int i0   = blockIdx.x * 32;
    const int mech = blockIdx.y;

    const float c0v = sc[(size_t)mech * NN + i0 + col];
    const float c1v = sc[(size_t)mech * NN + i0 + 16 + col];

    const u32x4* mr0 = reinterpret_cast<const u32x4*>(
        msk + (size_t)(i0 + col) * 128 + jq * 16);
    const u32x4* mr1 = reinterpret_cast<const u32x4*>(
        msk + (size_t)(i0 + 16 + col) * 128 + jq * 16);
    const float* pqb = spq + (size_t)mech * NN * 2 + (jq * 512 + kg * 8) * 2;
    const unsigned char* tb0 = htb + ((size_t)(mech * 128 + jq * 16)) * 4096
                             + col * 64 + kg * 16;

    f32x4 acc0[4], acc1[4];
    #pragma unroll
    for (int f = 0; f < 4; ++f) {
        acc0[f] = (f32x4){0.f, 0.f, 0.f, 0.f};
        acc1[f] = (f32x4){0.f, 0.f, 0.f, 0.f};
    }
    float z0 = 0.f, z1 = 0.f;

    s16x8 Ba[4], Bb[4];
    f32x4 Qa[4], Qb[4];
    LOADT(0, Ba);
    QLOAD(0, Qa);
    u32x4 m0n = mr0[0];
    u32x4 m1n = mr1[0];

    #pragma unroll 1
    for (int tq = 0; tq < 4; ++tq) {
        const int base = tq * 4;
        const u32x4 m0 = m0n, m1 = m1n;
        if (tq < 3) { m0n = mr0[tq + 1]; m1n = mr1[tq + 1]; }
        LOADT(base + 1, Bb); QLOAD(base + 1, Qb);
        COMPUTE(Ba, Qa, m0[0], m1[0]);
        LOADT(base + 2, Ba); QLOAD(base + 2, Qa);
        COMPUTE(Bb, Qb, m0[1], m1[1]);
        LOADT(base + 3, Bb); QLOAD(base + 3, Qb);
        COMPUTE(Ba, Qa, m0[2], m1[2]);
        if (tq < 3) { LOADT(base + 4, Ba); QLOAD(base + 4, Qa); }
        COMPUTE(Bb, Qb, m0[3], m1[3]);
    }

    // row-sum Z: lanes {r, r+16, r+32, r+48} hold the same row
    z0 += __shfl_xor(z0, 16); z0 += __shfl_xor(z0, 32);
    z1 += __shfl_xor(z1, 16); z1 += __shfl_xor(z1, 32);

    // ---- epilogue: each wave writes its 8KB partial; parallel 8-way reduce ----
    float* my = accP + jq * 2048;
    #pragma unroll
    for (int f = 0; f < 4; ++f) {
        #pragma unroll
        for (int rr = 0; rr < 4; ++rr) {
            my[(kg * 4 + rr) * 64 + f * 16 + col]      = acc0[f][rr];
            my[(16 + kg * 4 + rr) * 64 + f * 16 + col] = acc1[f][rr];
        }
    }
    if (lane < 16) {
        zP[jq * 32 + lane]      = z0;
        zP[jq * 32 + 16 + lane] = z1;
    }
    __syncthreads();

    const int row = t >> 4;            // 0..31
    const int o0  = (t & 15) * 4;      // 0..60
    f32x4 s = (f32x4){0.f, 0.f, 0.f, 0.f};
    float z = 0.f;
    #pragma unroll
    for (int p = 0; p < 8; ++p) {
        s += *reinterpret_cast<const f32x4*>(accP + p * 2048 + row * 64 + o0);
        z += zP[p * 32 + row];
    }
    const float inv = 1.0f / z;
    f32x4 res;
    #pragma unroll
    for (int e = 0; e < 4; ++e) {
        const float v = s[e] * inv;
        res[e] = v > 0.f ? v : expm1f(v);
    }
    *reinterpret_cast<f32x4*>(out + (size_t)(i0 + row) * 256 + mech * 64 + o0) = res;
}

extern "C" void kernel_launch(void* const* d_in, const int* in_sizes, int n_in,
                              void* d_out, int out_size, void* d_ws, size_t ws_size,
                              hipStream_t stream) {
    const float* x   = (const float*)d_in[0];
    const int*   adj = (const int*)d_in[1];
    const float* W   = (const float*)d_in[2];
    const float* a1  = (const float*)d_in[3];
    const float* a2  = (const float*)d_in[4];
    const float* Wc  = (const float*)d_in[5];
    const float* bc  = (const float*)d_in[6];
    float* out = (float*)d_out;

    float* wsf    = (float*)d_ws;
    float* part   = wsf;
    float* scv    = wsf + 16896;
    float* spq    = wsf + 33280;
    unsigned char* htb = (unsigned char*)(wsf + 66048);
    unsigned long long* msk = (unsigned long long*)(htb + (size_t)2097152);

    (void)hipFuncSetAttribute((const void*)k_attn,
                              hipFuncAttributeMaxDynamicSharedMemorySize, 66560);

    k_prep<<<1088, 256, 0, stream>>>(adj, msk, x, part);
    k_filmc<<<dim3(128, 4), 256, 0, stream>>>(x, W, a1, a2, part, Wc, bc, scv, spq, htb);
    k_attn<<<dim3(128, 4), 512, 66560, stream>>>((const unsigned int*)msk, scv, spq, htb, out);
}

// Round 8
// 79.013 us; speedup vs baseline: 2.0811x; 1.1836x over previous
//
#include <hip/hip_runtime.h>
#include <hip/hip_bf16.h>

// Problem constants
#define NN    4096
#define INS_  256
#define OUTS_ 64
#define MM    4
#define LOG2E 1.4426950408889634f

typedef float f32x4 __attribute__((ext_vector_type(4)));
typedef short s16x8 __attribute__((ext_vector_type(8)));
typedef unsigned int u32x4 __attribute__((ext_vector_type(4)));

typedef const __attribute__((address_space(1))) unsigned char glob_u8;
typedef __attribute__((address_space(3))) unsigned char lds_u8;

__device__ __forceinline__ void stage16(const void* g, void* l) {
    __builtin_amdgcn_global_load_lds((glob_u8*)g, (lds_u8*)l, 16, 0, 0);
}

__device__ __forceinline__ unsigned int cvt_pk_bf16(float a, float b) {
    unsigned int r;
    asm("v_cvt_pk_bf16_f32 %0, %1, %2" : "=v"(r) : "v"(a), "v"(b));
    return r;
}

// pack two f32 into bf16x2 (RNE) - VALU fallback used in k_filmc (not hot)
__device__ __forceinline__ unsigned int pack_bf16(float a, float b) {
    unsigned int ua = __builtin_bit_cast(unsigned int, a);
    unsigned int ub = __builtin_bit_cast(unsigned int, b);
    ua = (ua + 0x7FFFu + ((ua >> 16) & 1u)) >> 16;
    ub = (ub + 0x7FFFu + ((ub >> 16) & 1u)) & 0xFFFF0000u;
    return ua | ub;
}

// keep w if bit e of mb set, else 0  (sign-extend bit + and)
__device__ __forceinline__ float mand(float w, unsigned mb, int e) {
    const int m = ((int)(mb << (31 - e))) >> 31;
    return __builtin_bit_cast(float, (__builtin_bit_cast(int, w) & m));
}

// build A-fragment: 8 weights max(P, c*Q) masked, packed to bf16; accumulate f32 Z
__device__ __forceinline__ s16x8 mk_af(float c, unsigned mb,
        const f32x4 q0, const f32x4 q1, const f32x4 q2, const f32x4 q3, float& z) {
    const float w0 = mand(fmaxf(q0[0], c * q0[1]), mb, 0);
    const float w1 = mand(fmaxf(q0[2], c * q0[3]), mb, 1);
    const float w2 = mand(fmaxf(q1[0], c * q1[1]), mb, 2);
    const float w3 = mand(fmaxf(q1[2], c * q1[3]), mb, 3);
    const float w4 = mand(fmaxf(q2[0], c * q2[1]), mb, 4);
    const float w5 = mand(fmaxf(q2[2], c * q2[3]), mb, 5);
    const float w6 = mand(fmaxf(q3[0], c * q3[1]), mb, 6);
    const float w7 = mand(fmaxf(q3[2], c * q3[3]), mb, 7);
    z += ((w0 + w1) + (w2 + w3)) + ((w4 + w5) + (w6 + w7));
    u32x4 au;
    au.x = cvt_pk_bf16(w0, w1);
    au.y = cvt_pk_bf16(w2, w3);
    au.z = cvt_pk_bf16(w4, w5);
    au.w = cvt_pk_bf16(w6, w7);
    return __builtin_bit_cast(s16x8, au);
}

// ws layout (floats):
//   [0,16384)       part float [64][256]  (partial column sums)
//   [16896,33280)   sc  float [M][N]   = V/U = 2^{-0.8 s'}
//   [33280,66048)   spq float2[M][N]   = {2^{d'}, 2^{0.2 d'}}
//   byte 264192     Ht bf16 tiles [m][jt=0..127][4KB]: tile(o,jj) at o*64+jj*2  (2 MB)
//   byte 2361344    adj bitmask [N][512B]                                       (2 MB)

// ---------- kernel 1: fused adj->bitmask pack (blocks 0..1023) + x column
//            partial sums (blocks 1024..1087) ----------
__global__ __launch_bounds__(256) void k_prep(const int* __restrict__ adj,
                                              unsigned long long* __restrict__ msk,
                                              const float* __restrict__ x,
                                              float* __restrict__ part) {
    const int b = blockIdx.x;
    if (b < 1024) {
        const int lane = threadIdx.x & 63;
        const int w    = threadIdx.x >> 6;
        const int r    = b * 4 + w;
        const int* __restrict__ row = adj + (size_t)r * NN;
        unsigned long long* mrow = msk + (size_t)r * 64;
        #pragma unroll 1
        for (int c0 = 0; c0 < 64; c0 += 16) {
            int a[16];
            #pragma unroll
            for (int k = 0; k < 16; ++k) a[k] = row[(c0 + k) * 64 + lane];
            unsigned long long m[16];
            #pragma unroll
            for (int k = 0; k < 16; ++k) m[k] = __ballot(a[k] != 0);
            if (lane == 0) {
                #pragma unroll
                for (int k = 0; k < 16; ++k) mrow[c0 + k] = m[k];
            }
        }
    } else {
        const int bb = b - 1024;
        const int t  = threadIdx.x;
        const int r0 = bb * 64;
        float s = 0.f;
        #pragma unroll 8
        for (int r = 0; r < 64; ++r) s += x[(size_t)(r0 + r) * INS_ + t];
        part[bb * INS_ + t] = s;
    }
}

// ---------- kernel 2: fused conditioner + FiLM; emit tiled Ht, sc, spq ----------
__global__ __launch_bounds__(256, 2) void k_filmc(
    const float* __restrict__ x, const float* __restrict__ W,
    const float* __restrict__ a1, const float* __restrict__ a2,
    const float* __restrict__ part, const float* __restrict__ Wc,
    const float* __restrict__ bc, float* __restrict__ sc,
    float* __restrict__ spq, unsigned char* __restrict__ htb)
{
    __shared__ float wlds[INS_ * OUTS_];     // 64 KB: W[m] as [i][o]
    __shared__ float sp[INS_];
    __shared__ float pg[256];
    __shared__ float gg[64], bbv[64];

    const int t  = threadIdx.x;
    const int o  = t & 63;
    const int wv = __builtin_amdgcn_readfirstlane(t >> 6);   // wave 0..3
    const int m  = blockIdx.y;
    const int n0 = blockIdx.x * 32 + wv * 8;                 // this wave's 8 rows

    // async-stage W[m] (64 KB) into LDS: 16 x (256 thr x 16B)
    {
        const unsigned char* wsrc = (const unsigned char*)W + (size_t)m * 65536 + t * 16;
        unsigned char* wdst = (unsigned char*)wlds + t * 16;
        #pragma unroll
        for (int it = 0; it < 16; ++it)
            stage16(wsrc + it * 4096, wdst + it * 4096);
    }

    // conditioner: reduce partial column sums (all 256 threads)
    {
        float s = 0.f;
        #pragma unroll 8
        for (int b = 0; b < 64; ++b) s += part[b * INS_ + t];
        sp[t] = s * (1.0f / NN);
    }
    __syncthreads();   // sp ready (also drains W staging vmcnt)

    // split-K conditioner dot: 256 threads cover 128 outputs x 2 K-halves
    {
        const int half = t >> 7;            // 0/1
        const int idx  = t & 127;           // output index
        const int col  = m * 64 + (idx & 63) + ((idx & 64) ? 256 : 0);
        float acc = (half == 0) ? bc[col] : 0.f;
        const int ib = half * 128;
        #pragma unroll 8
        for (int i = 0; i < 128; ++i)
            acc = fmaf(sp[ib + i], Wc[(size_t)(ib + i) * 512 + col], acc);
        pg[t] = acc;
    }
    __syncthreads();
    if (t < 128) {
        const float v = pg[t] + pg[t + 128];
        if (t < 64) gg[t] = v; else bbv[t - 64] = v;
    }
    __syncthreads();

    // main x@W loop: wl from LDS (conflict-free), x rows via scalar loads
    float acc[8];
    #pragma unroll
    for (int k = 0; k < 8; ++k) acc[k] = 0.f;

    const float* xp = x + (size_t)n0 * INS_;

    #pragma unroll 4
    for (int i = 0; i < INS_; ++i) {
        const float wl = wlds[i * 64 + o];
        #pragma unroll
        for (int k = 0; k < 8; ++k)
            acc[k] = fmaf(xp[k * INS_ + i], wl, acc[k]);
    }

    const float ga  = gg[o];
    const float be  = bbv[o];
    const float va1 = a1[m * 64 + o];
    const float va2 = a2[m * 64 + o];

    float h[8], sv[8], dv[8];
    #pragma unroll
    for (int k = 0; k < 8; ++k) h[k] = fmaf(ga, acc[k], be);

    #pragma unroll
    for (int k = 0; k < 8; ++k) {
        float s1 = h[k] * va1;
        float s2 = h[k] * va2;
        #pragma unroll
        for (int off = 1; off < 64; off <<= 1) {
            s1 += __shfl_xor(s1, off);
            s2 += __shfl_xor(s2, off);
        }
        sv[k] = s1; dv[k] = s2;
    }

    // tile store: tile jt = blockIdx.x, rows jj = wv*8..wv*8+7
    u32x4 upk;
    upk.x = pack_bf16(h[0], h[1]);
    upk.y = pack_bf16(h[2], h[3]);
    upk.z = pack_bf16(h[4], h[5]);
    upk.w = pack_bf16(h[6], h[7]);
    const size_t phys = ((size_t)(m * 128 + blockIdx.x)) * 4096 + o * 64 + wv * 16;
    *reinterpret_cast<u32x4*>(htb + phys) = upk;

    // sc / spq
    const int lk = o & 7;
    float ssel = sv[0], dsel = dv[0];
    #pragma unroll
    for (int k = 1; k < 8; ++k) {
        if (lk == k) { ssel = sv[k]; dsel = dv[k]; }
    }
    if (o < 8) {
        sc[(size_t)m * NN + n0 + lk] = exp2f(-0.8f * LOG2E * ssel);
    } else if (o < 16) {
        const float spv = dsel * LOG2E;
        float2 ex = make_float2(exp2f(spv), exp2f(0.2f * spv));
        *reinterpret_cast<float2*>(&spq[(size_t)(m * NN + n0 + lk) * 2]) = ex;
    }
}

// ---------- kernel 3: fused masked softmax + PV ----------
// grid (128, 4): x = i-tile (32 rows), y = mech. 512 thr = 8 waves = 8 j-windows of 512.
// Each wave: 2 i-subtiles of 16, 16 tn iterations of 32 j, B+Q ping-pong prefetch.
#define LOADT(tn, B) do {                                                  \
    const unsigned char* tb_ = tb0 + (size_t)(tn) * 4096;                  \
    B[0] = *reinterpret_cast<const s16x8*>(tb_);                           \
    B[1] = *reinterpret_cast<const s16x8*>(tb_ + 1024);                    \
    B[2] = *reinterpret_cast<const s16x8*>(tb_ + 2048);                    \
    B[3] = *reinterpret_cast<const s16x8*>(tb_ + 3072);                    \
} while (0)

#define QLOAD(tn, Q) do {                                                  \
    const float* qp_ = pqb + (tn) * 64;                                    \
    Q[0] = *reinterpret_cast<const f32x4*>(qp_);                           \
    Q[1] = *reinterpret_cast<const f32x4*>(qp_ + 4);                       \
    Q[2] = *reinterpret_cast<const f32x4*>(qp_ + 8);                       \
    Q[3] = *reinterpret_cast<const f32x4*>(qp_ + 12);                      \
} while (0)

#define COMPUTE(B, Q, mw0, mw1) do {                                       \
    const s16x8 Af0_ = mk_af(c0v, (mw0) >> sh, Q[0], Q[1], Q[2], Q[3], z0);\
    const s16x8 Af1_ = mk_af(c1v, (mw1) >> sh, Q[0], Q[1], Q[2], Q[3], z1);\
    acc0[0] = __builtin_amdgcn_mfma_f32_16x16x32_bf16(Af0_, B[0], acc0[0], 0, 0, 0); \
    acc0[1] = __builtin_amdgcn_mfma_f32_16x16x32_bf16(Af0_, B[1], acc0[1], 0, 0, 0); \
    acc0[2] = __builtin_amdgcn_mfma_f32_16x16x32_bf16(Af0_, B[2], acc0[2], 0, 0, 0); \
    acc0[3] = __builtin_amdgcn_mfma_f32_16x16x32_bf16(Af0_, B[3], acc0[3], 0, 0, 0); \
    acc1[0] = __builtin_amdgcn_mfma_f32_16x16x32_bf16(Af1_, B[0], acc1[0], 0, 0, 0); \
    acc1[1] = __builtin_amdgcn_mfma_f32_16x16x32_bf16(Af1_, B[1], acc1[1], 0, 0, 0); \
    acc1[2] = __builtin_amdgcn_mfma_f32_16x16x32_bf16(Af1_, B[2], acc1[2], 0, 0, 0); \
    acc1[3] = __builtin_amdgcn_mfma_f32_16x16x32_bf16(Af1_, B[3], acc1[3], 0, 0, 0); \
} while (0)

__global__ __launch_bounds__(512, 2) void k_attn(
    const unsigned int* __restrict__ msk, const float* __restrict__ sc,
    const float* __restrict__ spq, const unsigned char* __restrict__ htb,
    float* __restrict__ out)
{
    extern __shared__ float lds[];           // accP[8][2048] + zP[8][32]
    float* accP = lds;
    float* zP   = lds + 8 * 2048;

    const int t    = threadIdx.x;
    const int lane = t & 63;
    const int jq   = __builtin_amdgcn_readfirstlane(t >> 6); // wave = j-window
    const int col  = lane & 15;
    const int kg   = lane >> 4;
    const int sh   = kg * 8;
    const int i0   = blockIdx.x * 32;
    const int mech = blockIdx.y;

    const float c0v = sc[(size_t)mech * NN + i0 + col];
    const float c1v = sc[(size_t)mech * NN + i0 + 16 + col];

    const u32x4* mr0 = reinterpret_cast<const u32x4*>(
        msk + (size_t)(i0 + col) * 128 + jq * 16);
    const u32x4* mr1 = reinterpret_cast<const u32x4*>(
        msk + (size_t)(i0 + 16 + col) * 128 + jq * 16);
    const float* pqb = spq + (size_t)mech * NN * 2 + (jq * 512 + kg * 8) * 2;
    const unsigned char* tb0 = htb + ((size_t)(mech * 128 + jq * 16)) * 4096
                             + col * 64 + kg * 16;

    f32x4 acc0[4], acc1[4];
    #pragma unroll
    for (int f = 0; f < 4; ++f) {
        acc0[f] = (f32x4){0.f, 0.f, 0.f, 0.f};
        acc1[f] = (f32x4){0.f, 0.f, 0.f, 0.f};
    }
    float z0 = 0.f, z1 = 0.f;

    s16x8 Ba[4], Bb[4];
    f32x4 Qa[4], Qb[4];
    LOADT(0, Ba);
    QLOAD(0, Qa);
    u32x4 m0n = mr0[0];
    u32x4 m1n = mr1[0];

    #pragma unroll 1
    for (int tq = 0; tq < 4; ++tq) {
        const int base = tq * 4;
        const u32x4 m0 = m0n, m1 = m1n;
        if (tq < 3) { m0n = mr0[tq + 1]; m1n = mr1[tq + 1]; }
        LOADT(base + 1, Bb); QLOAD(base + 1, Qb);
        COMPUTE(Ba, Qa, m0[0], m1[0]);
        LOADT(base + 2, Ba); QLOAD(base + 2, Qa);
        COMPUTE(Bb, Qb, m0[1], m1[1]);
        LOADT(base + 3, Bb); QLOAD(base + 3, Qb);
        COMPUTE(Ba, Qa, m0[2], m1[2]);
        if (tq < 3) { LOADT(base + 4, Ba); QLOAD(base + 4, Qa); }
        COMPUTE(Bb, Qb, m0[3], m1[3]);
    }

    // row-sum Z: lanes {r, r+16, r+32, r+48} hold the same row
    z0 += __shfl_xor(z0, 16); z0 += __shfl_xor(z0, 32);
    z1 += __shfl_xor(z1, 16); z1 += __shfl_xor(z1, 32);

    // ---- epilogue: each wave writes its 8KB partial; parallel 8-way reduce ----
    float* my = accP + jq * 2048;
    #pragma unroll
    for (int f = 0; f < 4; ++f) {
        #pragma unroll
        for (int rr = 0; rr < 4; ++rr) {
            my[(kg * 4 + rr) * 64 + f * 16 + col]      = acc0[f][rr];
            my[(16 + kg * 4 + rr) * 64 + f * 16 + col] = acc1[f][rr];
        }
    }
    if (lane < 16) {
        zP[jq * 32 + lane]      = z0;
        zP[jq * 32 + 16 + lane] = z1;
    }
    __syncthreads();

    const int row = t >> 4;            // 0..31
    const int o0  = (t & 15) * 4;      // 0..60
    f32x4 s = (f32x4){0.f, 0.f, 0.f, 0.f};
    float z = 0.f;
    #pragma unroll
    for (int p = 0; p < 8; ++p) {
        s += *reinterpret_cast<const f32x4*>(accP + p * 2048 + row * 64 + o0);
        z += zP[p * 32 + row];
    }
    const float inv = 1.0f / z;
    f32x4 res;
    #pragma unroll
    for (int e = 0; e < 4; ++e) {
        const float v = s[e] * inv;
        res[e] = v > 0.f ? v : expm1f(v);
    }
    *reinterpret_cast<f32x4*>(out + (size_t)(i0 + row) * 256 + mech * 64 + o0) = res;
}

extern "C" void kernel_launch(void* const* d_in, const int* in_sizes, int n_in,
                              void* d_out, int out_size, void* d_ws, size_t ws_size,
                              hipStream_t stream) {
    const float* x   = (const float*)d_in[0];
    const int*   adj = (const int*)d_in[1];
    const float* W   = (const float*)d_in[2];
    const float* a1  = (const float*)d_in[3];
    const float* a2  = (const float*)d_in[4];
    const float* Wc  = (const float*)d_in[5];
    const float* bc  = (const float*)d_in[6];
    float* out = (float*)d_out;

    float* wsf    = (float*)d_ws;
    float* part   = wsf;
    float* scv    = wsf + 16896;
    float* spq    = wsf + 33280;
    unsigned char* htb = (unsigned char*)(wsf + 66048);
    unsigned long long* msk = (unsigned long long*)(htb + (size_t)2097152);

    (void)hipFuncSetAttribute((const void*)k_attn,
                              hipFuncAttributeMaxDynamicSharedMemorySize, 66560);

    k_prep<<<1088, 256, 0, stream>>>(adj, msk, x, part);
    k_filmc<<<dim3(128, 4), 256, 0, stream>>>(x, W, a1, a2, part, Wc, bc, scv, spq, htb);
    k_attn<<<dim3(128, 4), 512, 66560, stream>>>((const unsigned int*)msk, scv, spq, htb, out);
}